// Round 7
// baseline (455.442 us; speedup 1.0000x reference)
//
#include <hip/hip_runtime.h>

#define NN 50000
#define NE 800000
#define NG 256
#define DD 256
#define NL 3
#define BN_EPS 1e-5f
#define MPAD 50048   // 391 * 128
#define CAP 96       // per-node edge bucket capacity (Poisson(16) tail @96 ~ 1e-40)
#define NMB 391      // MPAD / 128 (GEMM m-blocks)

typedef short bf16x8 __attribute__((ext_vector_type(8)));
typedef float f32x4 __attribute__((ext_vector_type(4)));
typedef unsigned short ushort8 __attribute__((ext_vector_type(8)));

__device__ __forceinline__ unsigned short f2bf(float f) {
    unsigned int u = __float_as_uint(f);
    u += 0x7FFFu + ((u >> 16) & 1u);
    return (unsigned short)(u >> 16);
}
__device__ __forceinline__ float bf2f(unsigned short s) {
    return __uint_as_float(((unsigned int)s) << 16);
}

// ---------- init: zero deg (doubles as scatter cursor) ----------
__global__ void k_init(int* __restrict__ deg) {
    int i = blockIdx.x * blockDim.x + threadIdx.x;
    if (i < NN) deg[i] = 0;
}

// one-pass CSR build: bucket scatter (u16 src); deg ends up as the in-degree
__global__ void k_scatter(const int* __restrict__ ei, int* __restrict__ deg,
                          unsigned short* __restrict__ elist) {
    int e = blockIdx.x * blockDim.x + threadIdx.x;
    if (e >= NE) return;
    int s = ei[e];          // src  (< 65536)
    int d = ei[NE + e];     // dst
    int pos = atomicAdd(&deg[d], 1);
    elist[(size_t)d * CAP + pos] = (unsigned short)s;
}

// graph boundaries via binary search over sorted batch
__global__ void k_gbounds(const int* __restrict__ batch, int* __restrict__ gstart) {
    int g = threadIdx.x;   // 0..255
    int lo = 0, hi = NN;
    while (lo < hi) {
        int mid = (lo + hi) >> 1;
        if (batch[mid] < g) lo = mid + 1; else hi = mid;
    }
    gstart[g] = lo;
    if (g == 0) gstart[NG] = NN;
}

// ---------- conversions ----------
__global__ void k_f2bf(const float* __restrict__ in, unsigned short* __restrict__ out, int n4) {
    int i = blockIdx.x * blockDim.x + threadIdx.x;
    if (i >= n4) return;
    float4 v = ((const float4*)in)[i];
    ushort4 o;
    o.x = f2bf(v.x); o.y = f2bf(v.y); o.z = f2bf(v.z); o.w = f2bf(v.w);
    ((ushort4*)out)[i] = o;
}

__global__ void k_zpad(unsigned short* p) {
    int i = blockIdx.x * blockDim.x + threadIdx.x;
    const int total = (MPAD - NN) * DD;
    if (i < total) p[NN * DD + i] = 0;
}

// wt[mat][n][k] = w[mat][k][n] as bf16; mats 0..2 = w1 layers, 3..5 = w2 layers
__global__ void k_wconv(const float* __restrict__ w1, const float* __restrict__ w2,
                        unsigned short* __restrict__ wt) {
    int flat = blockIdx.x * blockDim.x + threadIdx.x;
    if (flat >= 6 * 65536) return;
    int mat = flat >> 16;
    int n = (flat >> 8) & 255;
    int k = flat & 255;
    const float* src = (mat < 3) ? (w1 + ((size_t)mat << 16)) : (w2 + ((size_t)(mat - 3) << 16));
    wt[flat] = f2bf(src[k * 256 + n]);
}

// ---------- aggregation: z0 = h + sum_{src} h[src], bf16 in/out, fp32 accum ----------
// 4 waves per block (one node per wave) for full CU wave occupancy; unroll-8 gather
// with vectorized elist read; accumulation strictly in elist order (bitwise stable).
__global__ __launch_bounds__(256) void k_agg_bf(const unsigned short* __restrict__ h,
                                                const int* __restrict__ deg,
                                                const unsigned short* __restrict__ elist,
                                                unsigned short* __restrict__ z0) {
    int wave = threadIdx.x >> 6;
    int lane = threadIdx.x & 63;
    int node = blockIdx.x * 4 + wave;   // NN = 12500*4, always in range
    const ushort4* h4 = (const ushort4*)h;
    ushort4 own = h4[(size_t)node * 64 + lane];
    float a0 = bf2f(own.x), a1 = bf2f(own.y), a2 = bf2f(own.z), a3 = bf2f(own.w);
    int n = deg[node];
    const unsigned short* el = elist + (size_t)node * CAP;
    int i = 0;
    for (; i + 8 <= n; i += 8) {
        ushort8 sv = *(const ushort8*)(el + i);   // 16B aligned (CAP*2=192)
        ushort4 v0 = h4[(size_t)sv[0] * 64 + lane];
        ushort4 v1 = h4[(size_t)sv[1] * 64 + lane];
        ushort4 v2 = h4[(size_t)sv[2] * 64 + lane];
        ushort4 v3 = h4[(size_t)sv[3] * 64 + lane];
        ushort4 v4 = h4[(size_t)sv[4] * 64 + lane];
        ushort4 v5 = h4[(size_t)sv[5] * 64 + lane];
        ushort4 v6 = h4[(size_t)sv[6] * 64 + lane];
        ushort4 v7 = h4[(size_t)sv[7] * 64 + lane];
        a0 += bf2f(v0.x); a1 += bf2f(v0.y); a2 += bf2f(v0.z); a3 += bf2f(v0.w);
        a0 += bf2f(v1.x); a1 += bf2f(v1.y); a2 += bf2f(v1.z); a3 += bf2f(v1.w);
        a0 += bf2f(v2.x); a1 += bf2f(v2.y); a2 += bf2f(v2.z); a3 += bf2f(v2.w);
        a0 += bf2f(v3.x); a1 += bf2f(v3.y); a2 += bf2f(v3.z); a3 += bf2f(v3.w);
        a0 += bf2f(v4.x); a1 += bf2f(v4.y); a2 += bf2f(v4.z); a3 += bf2f(v4.w);
        a0 += bf2f(v5.x); a1 += bf2f(v5.y); a2 += bf2f(v5.z); a3 += bf2f(v5.w);
        a0 += bf2f(v6.x); a1 += bf2f(v6.y); a2 += bf2f(v6.z); a3 += bf2f(v6.w);
        a0 += bf2f(v7.x); a1 += bf2f(v7.y); a2 += bf2f(v7.z); a3 += bf2f(v7.w);
    }
    for (; i < n; ++i) {
        int s = el[i];
        ushort4 v = h4[(size_t)s * 64 + lane];
        a0 += bf2f(v.x); a1 += bf2f(v.y); a2 += bf2f(v.z); a3 += bf2f(v.w);
    }
    ushort4 o;
    o.x = f2bf(a0); o.y = f2bf(a1); o.z = f2bf(a2); o.w = f2bf(a3);
    ((ushort4*)z0)[(size_t)node * 64 + lane] = o;
}

// ---------- bf16 MFMA GEMM: C = relu(A @ W + bias), optional fused BN partial stats ----------
#define GBM 128
#define GBK 64
template<int OUT_BF16, int STATS>
__global__ __launch_bounds__(256) void k_mfma_gemm(const unsigned short* __restrict__ A,
                                                   const unsigned short* __restrict__ BT,
                                                   const float* __restrict__ bias,
                                                   void* __restrict__ Cout,
                                                   float* __restrict__ pstat) {
    __shared__ short As[GBM * GBK];
    __shared__ short Bs[GBM * GBK];
    __shared__ float spart[2][128][2];   // [wr][col_local][sum|sumsq]
    int tid = threadIdx.x;
    int lane = tid & 63;
    int wave = tid >> 6;
    int wr = wave >> 1, wc = wave & 1;
    long m0 = (long)blockIdx.x * GBM;
    int n0 = blockIdx.y * GBM;
    const int r = lane & 15, hi = lane >> 4;

    f32x4 acc[4][4];
    #pragma unroll
    for (int m = 0; m < 4; ++m)
        #pragma unroll
        for (int n = 0; n < 4; ++n)
            acc[m][n] = (f32x4){0.f, 0.f, 0.f, 0.f};

    for (int k0 = 0; k0 < DD; k0 += GBK) {
        #pragma unroll
        for (int p = 0; p < 4; ++p) {
            int flat = p * 256 + tid;
            int row = flat >> 3;
            int c8 = flat & 7;
            int slot = c8 ^ (row & 7);
            bf16x8 va = *(const bf16x8*)(A + (m0 + row) * DD + k0 + c8 * 8);
            *(bf16x8*)(As + row * GBK + slot * 8) = va;
            bf16x8 vb = *(const bf16x8*)(BT + (long)(n0 + row) * DD + k0 + c8 * 8);
            *(bf16x8*)(Bs + row * GBK + slot * 8) = vb;
        }
        __syncthreads();

        bf16x8 af[4][2], bfr[4][2];
        #pragma unroll
        for (int m = 0; m < 4; ++m) {
            int row = wr * 64 + m * 16 + r;
            #pragma unroll
            for (int kk = 0; kk < 2; ++kk) {
                int slot = (kk * 4 + hi) ^ (row & 7);
                af[m][kk] = *(const bf16x8*)(As + row * GBK + slot * 8);
            }
        }
        #pragma unroll
        for (int n = 0; n < 4; ++n) {
            int col = wc * 64 + n * 16 + r;
            #pragma unroll
            for (int kk = 0; kk < 2; ++kk) {
                int slot = (kk * 4 + hi) ^ (col & 7);
                bfr[n][kk] = *(const bf16x8*)(Bs + col * GBK + slot * 8);
            }
        }
        #pragma unroll
        for (int kk = 0; kk < 2; ++kk)
            #pragma unroll
            for (int m = 0; m < 4; ++m)
                #pragma unroll
                for (int n = 0; n < 4; ++n)
                    acc[m][n] = __builtin_amdgcn_mfma_f32_16x16x32_bf16(af[m][kk], bfr[n][kk], acc[m][n], 0, 0, 0);
        __syncthreads();
    }

    // epilogue: bias + relu (+ per-block BN column partials)
    #pragma unroll
    for (int n = 0; n < 4; ++n) {
        int col = n0 + wc * 64 + n * 16 + r;
        float bv = bias[col];
        float cs = 0.f, cs2 = 0.f;
        #pragma unroll
        for (int m = 0; m < 4; ++m) {
            #pragma unroll
            for (int j = 0; j < 4; ++j) {
                long grow = m0 + wr * 64 + m * 16 + hi * 4 + j;
                float v = acc[m][n][j] + bv;
                v = v > 0.f ? v : 0.f;
                if (OUT_BF16) ((unsigned short*)Cout)[grow * DD + col] = f2bf(v);
                else          ((float*)Cout)[grow * DD + col] = v;
                if (STATS) {
                    float vm = (grow < NN) ? v : 0.f;
                    cs += vm; cs2 += vm * vm;
                }
            }
        }
        if (STATS) {
            cs  += __shfl_xor(cs, 16);  cs  += __shfl_xor(cs, 32);
            cs2 += __shfl_xor(cs2, 16); cs2 += __shfl_xor(cs2, 32);
            if (hi == 0) {
                spart[wr][wc * 64 + n * 16 + r][0] = cs;
                spart[wr][wc * 64 + n * 16 + r][1] = cs2;
            }
        }
    }
    if (STATS) {
        __syncthreads();
        if (tid < 128) {
            float s  = spart[0][tid][0] + spart[1][tid][0];
            float s2 = spart[0][tid][1] + spart[1][tid][1];
            pstat[(size_t)blockIdx.x * 512 + n0 + tid] = s;
            pstat[(size_t)blockIdx.x * 512 + 256 + n0 + tid] = s2;
        }
    }
}

// reduce per-block partials -> BN scale/shift (one block per column, fixed tree)
__global__ __launch_bounds__(256) void k_bnscale2(const float* __restrict__ pstat,
                                                  const float* __restrict__ gamma,
                                                  const float* __restrict__ beta,
                                                  float* __restrict__ ss) {
    int c = blockIdx.x;
    int t = threadIdx.x;
    float s = 0.f, s2 = 0.f;
    for (int mb = t; mb < NMB; mb += 256) {
        s  += pstat[(size_t)mb * 512 + c];
        s2 += pstat[(size_t)mb * 512 + 256 + c];
    }
    __shared__ float rs[256], rs2[256];
    rs[t] = s; rs2[t] = s2;
    __syncthreads();
    #pragma unroll
    for (int d = 128; d > 0; d >>= 1) {
        if (t < d) { rs[t] += rs[t + d]; rs2[t] += rs2[t + d]; }
        __syncthreads();
    }
    if (t == 0) {
        float mean = rs[0] * (1.0f / NN);
        float var = rs2[0] * (1.0f / NN) - mean * mean;
        float sc = gamma[c] * rsqrtf(var + BN_EPS);
        ss[c] = sc;
        ss[DD + c] = beta[c] - mean * sc;
    }
}

// fused BN-apply + bf16 emit + global_add_pool; 512 thr: quad q (64) x rowgroup rg (8)
__global__ __launch_bounds__(512) void k_bnpool(const float* __restrict__ z,
                                                const float* __restrict__ ss,
                                                const int* __restrict__ gstart,
                                                unsigned short* __restrict__ hbf,
                                                float* __restrict__ out, int layer) {
    __shared__ float4 red[8][64];
    int g = blockIdx.x;
    int t = threadIdx.x;
    int q = t & 63, rg = t >> 6;
    float4 sc = ((const float4*)ss)[q];
    float4 sh = ((const float4*)(ss + DD))[q];
    int lo = gstart[g], hi = gstart[g + 1];
    float4 s = {0.f, 0.f, 0.f, 0.f};
    const float4* z4 = (const float4*)z;
    ushort4* h4 = (ushort4*)hbf;
    for (int r = lo + rg; r < hi; r += 8) {
        float4 v = z4[r * 64 + q];
        v.x = v.x * sc.x + sh.x;
        v.y = v.y * sc.y + sh.y;
        v.z = v.z * sc.z + sh.z;
        v.w = v.w * sc.w + sh.w;
        s.x += v.x; s.y += v.y; s.z += v.z; s.w += v.w;
        ushort4 o;
        o.x = f2bf(v.x); o.y = f2bf(v.y); o.z = f2bf(v.z); o.w = f2bf(v.w);
        h4[r * 64 + q] = o;
    }
    red[rg][q] = s;
    __syncthreads();
    if (rg < 4) {
        float4 a = red[rg][q], b = red[rg + 4][q];
        a.x += b.x; a.y += b.y; a.z += b.z; a.w += b.w;
        red[rg][q] = a;
    }
    __syncthreads();
    if (rg < 2) {
        float4 a = red[rg][q], b = red[rg + 2][q];
        a.x += b.x; a.y += b.y; a.z += b.z; a.w += b.w;
        red[rg][q] = a;
    }
    __syncthreads();
    if (rg == 0) {
        float4 a = red[0][q], b = red[1][q];
        a.x += b.x; a.y += b.y; a.z += b.z; a.w += b.w;
        ((float4*)(out + (size_t)g * (NL * DD) + layer * DD))[q] = a;
    }
}

extern "C" void kernel_launch(void* const* d_in, const int* in_sizes, int n_in,
                              void* d_out, int out_size, void* d_ws, size_t ws_size,
                              hipStream_t stream) {
    const float* x     = (const float*)d_in[0];
    const int*   ei    = (const int*)d_in[1];
    const int*   batch = (const int*)d_in[2];
    const float* w1    = (const float*)d_in[3];
    const float* b1    = (const float*)d_in[4];
    const float* w2    = (const float*)d_in[5];
    const float* b2    = (const float*)d_in[6];
    const float* gamma = (const float*)d_in[7];
    const float* beta  = (const float*)d_in[8];
    float* out = (float*)d_out;

    char* ws = (char*)d_ws;
    size_t off = 0;
    auto alloc = [&](size_t bytes) -> void* {
        void* p = ws + off;
        off += (bytes + 255) & ~size_t(255);
        return p;
    };
    float*          buf0 = (float*)alloc((size_t)MPAD * DD * 4);          // fp32 GEMM2 out
    unsigned short* zbf  = (unsigned short*)alloc((size_t)MPAD * DD * 2); // agg out (GEMM1 A)
    unsigned short* h1bf = (unsigned short*)alloc((size_t)MPAD * DD * 2); // GEMM1 out (GEMM2 A)
    unsigned short* hbf  = (unsigned short*)alloc((size_t)NN * DD * 2);   // h as bf16
    unsigned short* wt   = (unsigned short*)alloc((size_t)6 * DD * DD * 2);
    int* deg    = (int*)alloc((size_t)NN * 4);
    unsigned short* elist = (unsigned short*)alloc((size_t)NN * CAP * 2);
    int* gstart = (int*)alloc((size_t)(NG + 1) * 4);
    float* pstat = (float*)alloc((size_t)NMB * 512 * 4);
    float* ss   = (float*)alloc(2 * DD * 4);

    // CSR (one atomic pass) + graph boundaries (binary search)
    k_init<<<(NN + 255) / 256, 256, 0, stream>>>(deg);
    k_scatter<<<(NE + 255) / 256, 256, 0, stream>>>(ei, deg, elist);
    k_gbounds<<<1, 256, 0, stream>>>(batch, gstart);

    // weight transpose+convert, x -> bf16, zero pad rows of zbf
    k_wconv<<<(6 * 65536 + 255) / 256, 256, 0, stream>>>(w1, w2, wt);
    k_f2bf<<<(NN * DD / 4 + 255) / 256, 256, 0, stream>>>(x, hbf, NN * DD / 4);
    k_zpad<<<((MPAD - NN) * DD + 255) / 256, 256, 0, stream>>>(zbf);

    dim3 ggrid(MPAD / GBM, DD / GBM);
    for (int l = 0; l < NL; ++l) {
        k_agg_bf<<<NN / 4, 256, 0, stream>>>(hbf, deg, elist, zbf);
        k_mfma_gemm<1, 0><<<ggrid, 256, 0, stream>>>(zbf, wt + (size_t)l * DD * DD, b1 + l * DD, h1bf, nullptr);
        k_mfma_gemm<0, 1><<<ggrid, 256, 0, stream>>>(h1bf, wt + (size_t)(3 + l) * DD * DD, b2 + l * DD, buf0, pstat);
        k_bnscale2<<<DD, 256, 0, stream>>>(pstat, gamma + l * DD, beta + l * DD, ss);
        k_bnpool<<<NG, 512, 0, stream>>>(buf0, ss, gstart, hbf, out, l);
    }
}

// Round 8
// 450.218 us; speedup vs baseline: 1.0116x; 1.0116x over previous
//
#include <hip/hip_runtime.h>

#define NN 50000
#define NE 800000
#define NG 256
#define DD 256
#define NL 3
#define BN_EPS 1e-5f
#define MPAD 50048   // 391 * 128
#define CAP 96       // per-node edge bucket capacity (Poisson(16) tail @96 ~ 1e-40)
#define NMB 391      // MPAD / 128 (GEMM m-blocks)

typedef short bf16x8 __attribute__((ext_vector_type(8)));
typedef float f32x4 __attribute__((ext_vector_type(4)));
typedef unsigned short ushort8 __attribute__((ext_vector_type(8)));

__device__ __forceinline__ unsigned short f2bf(float f) {
    unsigned int u = __float_as_uint(f);
    u += 0x7FFFu + ((u >> 16) & 1u);
    return (unsigned short)(u >> 16);
}
__device__ __forceinline__ float bf2f(unsigned short s) {
    return __uint_as_float(((unsigned int)s) << 16);
}

// ---------- init: zero deg (doubles as scatter cursor) ----------
__global__ void k_init(int* __restrict__ deg) {
    int i = blockIdx.x * blockDim.x + threadIdx.x;
    if (i < NN) deg[i] = 0;
}

// one-pass CSR build: bucket scatter (u16 src); deg ends up as the in-degree
__global__ void k_scatter(const int* __restrict__ ei, int* __restrict__ deg,
                          unsigned short* __restrict__ elist) {
    int e = blockIdx.x * blockDim.x + threadIdx.x;
    if (e >= NE) return;
    int s = ei[e];          // src  (< 65536)
    int d = ei[NE + e];     // dst
    int pos = atomicAdd(&deg[d], 1);
    elist[(size_t)d * CAP + pos] = (unsigned short)s;
}

// graph boundaries via binary search over sorted batch
__global__ void k_gbounds(const int* __restrict__ batch, int* __restrict__ gstart) {
    int g = threadIdx.x;   // 0..255
    int lo = 0, hi = NN;
    while (lo < hi) {
        int mid = (lo + hi) >> 1;
        if (batch[mid] < g) lo = mid + 1; else hi = mid;
    }
    gstart[g] = lo;
    if (g == 0) gstart[NG] = NN;
}

// ---------- conversions ----------
__global__ void k_f2bf(const float* __restrict__ in, unsigned short* __restrict__ out, int n4) {
    int i = blockIdx.x * blockDim.x + threadIdx.x;
    if (i >= n4) return;
    float4 v = ((const float4*)in)[i];
    ushort4 o;
    o.x = f2bf(v.x); o.y = f2bf(v.y); o.z = f2bf(v.z); o.w = f2bf(v.w);
    ((ushort4*)out)[i] = o;
}

// zero the sentinel row (index NN) of hbf
__global__ void k_zrow(unsigned short* __restrict__ hbf) {
    hbf[(size_t)NN * DD + threadIdx.x] = 0;
}

__global__ void k_zpad(unsigned short* p) {
    int i = blockIdx.x * blockDim.x + threadIdx.x;
    const int total = (MPAD - NN) * DD;
    if (i < total) p[NN * DD + i] = 0;
}

// wt[mat][n][k] = w[mat][k][n] as bf16; mats 0..2 = w1 layers, 3..5 = w2 layers
__global__ void k_wconv(const float* __restrict__ w1, const float* __restrict__ w2,
                        unsigned short* __restrict__ wt) {
    int flat = blockIdx.x * blockDim.x + threadIdx.x;
    if (flat >= 6 * 65536) return;
    int mat = flat >> 16;
    int n = (flat >> 8) & 255;
    int k = flat & 255;
    const float* src = (mat < 3) ? (w1 + ((size_t)mat << 16)) : (w2 + ((size_t)(mat - 3) << 16));
    wt[flat] = f2bf(src[k * 256 + n]);
}

// ---------- aggregation: z0 = h + sum_{src} h[src], bf16 in/out, fp32 accum ----------
// 2 rows per VMEM instruction: 16B/lane, 32 lanes per row. Lane-half 0 accumulates
// own row + even-indexed edges, half 1 odd-indexed edges; combine via shfl_xor(32).
// Doubles bytes per memory-queue slot (queue-depth-limited kernel).
__global__ __launch_bounds__(256) void k_agg_bf(const unsigned short* __restrict__ h,
                                                const int* __restrict__ deg,
                                                const unsigned short* __restrict__ elist,
                                                unsigned short* __restrict__ z0) {
    int wave = threadIdx.x >> 6;
    int lane = threadIdx.x & 63;
    int node = blockIdx.x * 4 + wave;   // NN = 12500*4, always in range
    int chunk = lane & 31;              // 16B chunk within the 512B row
    int half = lane >> 5;               // 0: even edges (+own), 1: odd edges
    const ushort8* h8 = (const ushort8*)h;

    float acc[8];
    if (half == 0) {
        ushort8 own = h8[(size_t)node * 32 + chunk];
        #pragma unroll
        for (int j = 0; j < 8; ++j) acc[j] = bf2f(own[j]);
    } else {
        #pragma unroll
        for (int j = 0; j < 8; ++j) acc[j] = 0.f;
    }

    int n = deg[node];
    const unsigned short* el = elist + (size_t)node * CAP;
    int i = 0;
    for (; i + 8 <= n; i += 8) {
        ushort8 sv = *(const ushort8*)(el + i);   // 16B aligned (CAP*2=192)
        int i0 = half ? sv[1] : sv[0];
        int i1 = half ? sv[3] : sv[2];
        int i2 = half ? sv[5] : sv[4];
        int i3 = half ? sv[7] : sv[6];
        ushort8 r0 = h8[(size_t)i0 * 32 + chunk];
        ushort8 r1 = h8[(size_t)i1 * 32 + chunk];
        ushort8 r2 = h8[(size_t)i2 * 32 + chunk];
        ushort8 r3 = h8[(size_t)i3 * 32 + chunk];
        #pragma unroll
        for (int j = 0; j < 8; ++j) acc[j] += bf2f(r0[j]);
        #pragma unroll
        for (int j = 0; j < 8; ++j) acc[j] += bf2f(r1[j]);
        #pragma unroll
        for (int j = 0; j < 8; ++j) acc[j] += bf2f(r2[j]);
        #pragma unroll
        for (int j = 0; j < 8; ++j) acc[j] += bf2f(r3[j]);
    }
    for (; i < n; i += 2) {
        int s0 = el[i];
        int s1 = (i + 1 < n) ? (int)el[i + 1] : NN;   // sentinel zero row
        int idx = half ? s1 : s0;
        ushort8 r = h8[(size_t)idx * 32 + chunk];
        #pragma unroll
        for (int j = 0; j < 8; ++j) acc[j] += bf2f(r[j]);
    }

    // combine halves (fp add commutative -> both halves identical totals)
    ushort8 o;
    #pragma unroll
    for (int j = 0; j < 8; ++j) {
        float other = __shfl_xor(acc[j], 32);
        o[j] = f2bf(acc[j] + other);
    }
    if (half == 0) ((ushort8*)z0)[(size_t)node * 32 + chunk] = o;
}

// ---------- bf16 MFMA GEMM: C = relu(A @ W + bias), optional fused BN partial stats ----------
#define GBM 128
#define GBK 64
template<int OUT_BF16, int STATS>
__global__ __launch_bounds__(256) void k_mfma_gemm(const unsigned short* __restrict__ A,
                                                   const unsigned short* __restrict__ BT,
                                                   const float* __restrict__ bias,
                                                   void* __restrict__ Cout,
                                                   float* __restrict__ pstat) {
    __shared__ short As[GBM * GBK];
    __shared__ short Bs[GBM * GBK];
    __shared__ float spart[2][128][2];   // [wr][col_local][sum|sumsq]
    int tid = threadIdx.x;
    int lane = tid & 63;
    int wave = tid >> 6;
    int wr = wave >> 1, wc = wave & 1;
    long m0 = (long)blockIdx.x * GBM;
    int n0 = blockIdx.y * GBM;
    const int r = lane & 15, hi = lane >> 4;

    f32x4 acc[4][4];
    #pragma unroll
    for (int m = 0; m < 4; ++m)
        #pragma unroll
        for (int n = 0; n < 4; ++n)
            acc[m][n] = (f32x4){0.f, 0.f, 0.f, 0.f};

    for (int k0 = 0; k0 < DD; k0 += GBK) {
        #pragma unroll
        for (int p = 0; p < 4; ++p) {
            int flat = p * 256 + tid;
            int row = flat >> 3;
            int c8 = flat & 7;
            int slot = c8 ^ (row & 7);
            bf16x8 va = *(const bf16x8*)(A + (m0 + row) * DD + k0 + c8 * 8);
            *(bf16x8*)(As + row * GBK + slot * 8) = va;
            bf16x8 vb = *(const bf16x8*)(BT + (long)(n0 + row) * DD + k0 + c8 * 8);
            *(bf16x8*)(Bs + row * GBK + slot * 8) = vb;
        }
        __syncthreads();

        bf16x8 af[4][2], bfr[4][2];
        #pragma unroll
        for (int m = 0; m < 4; ++m) {
            int row = wr * 64 + m * 16 + r;
            #pragma unroll
            for (int kk = 0; kk < 2; ++kk) {
                int slot = (kk * 4 + hi) ^ (row & 7);
                af[m][kk] = *(const bf16x8*)(As + row * GBK + slot * 8);
            }
        }
        #pragma unroll
        for (int n = 0; n < 4; ++n) {
            int col = wc * 64 + n * 16 + r;
            #pragma unroll
            for (int kk = 0; kk < 2; ++kk) {
                int slot = (kk * 4 + hi) ^ (col & 7);
                bfr[n][kk] = *(const bf16x8*)(Bs + col * GBK + slot * 8);
            }
        }
        #pragma unroll
        for (int kk = 0; kk < 2; ++kk)
            #pragma unroll
            for (int m = 0; m < 4; ++m)
                #pragma unroll
                for (int n = 0; n < 4; ++n)
                    acc[m][n] = __builtin_amdgcn_mfma_f32_16x16x32_bf16(af[m][kk], bfr[n][kk], acc[m][n], 0, 0, 0);
        __syncthreads();
    }

    // epilogue: bias + relu (+ per-block BN column partials)
    #pragma unroll
    for (int n = 0; n < 4; ++n) {
        int col = n0 + wc * 64 + n * 16 + r;
        float bv = bias[col];
        float cs = 0.f, cs2 = 0.f;
        #pragma unroll
        for (int m = 0; m < 4; ++m) {
            #pragma unroll
            for (int j = 0; j < 4; ++j) {
                long grow = m0 + wr * 64 + m * 16 + hi * 4 + j;
                float v = acc[m][n][j] + bv;
                v = v > 0.f ? v : 0.f;
                if (OUT_BF16) ((unsigned short*)Cout)[grow * DD + col] = f2bf(v);
                else          ((float*)Cout)[grow * DD + col] = v;
                if (STATS) {
                    float vm = (grow < NN) ? v : 0.f;
                    cs += vm; cs2 += vm * vm;
                }
            }
        }
        if (STATS) {
            cs  += __shfl_xor(cs, 16);  cs  += __shfl_xor(cs, 32);
            cs2 += __shfl_xor(cs2, 16); cs2 += __shfl_xor(cs2, 32);
            if (hi == 0) {
                spart[wr][wc * 64 + n * 16 + r][0] = cs;
                spart[wr][wc * 64 + n * 16 + r][1] = cs2;
            }
        }
    }
    if (STATS) {
        __syncthreads();
        if (tid < 128) {
            float s  = spart[0][tid][0] + spart[1][tid][0];
            float s2 = spart[0][tid][1] + spart[1][tid][1];
            pstat[(size_t)blockIdx.x * 512 + n0 + tid] = s;
            pstat[(size_t)blockIdx.x * 512 + 256 + n0 + tid] = s2;
        }
    }
}

// reduce per-block partials -> BN scale/shift (one block per column, fixed tree)
__global__ __launch_bounds__(256) void k_bnscale2(const float* __restrict__ pstat,
                                                  const float* __restrict__ gamma,
                                                  const float* __restrict__ beta,
                                                  float* __restrict__ ss) {
    int c = blockIdx.x;
    int t = threadIdx.x;
    float s = 0.f, s2 = 0.f;
    for (int mb = t; mb < NMB; mb += 256) {
        s  += pstat[(size_t)mb * 512 + c];
        s2 += pstat[(size_t)mb * 512 + 256 + c];
    }
    __shared__ float rs[256], rs2[256];
    rs[t] = s; rs2[t] = s2;
    __syncthreads();
    #pragma unroll
    for (int d = 128; d > 0; d >>= 1) {
        if (t < d) { rs[t] += rs[t + d]; rs2[t] += rs2[t + d]; }
        __syncthreads();
    }
    if (t == 0) {
        float mean = rs[0] * (1.0f / NN);
        float var = rs2[0] * (1.0f / NN) - mean * mean;
        float sc = gamma[c] * rsqrtf(var + BN_EPS);
        ss[c] = sc;
        ss[DD + c] = beta[c] - mean * sc;
    }
}

// fused BN-apply + bf16 emit + global_add_pool; 512 thr: quad q (64) x rowgroup rg (8)
__global__ __launch_bounds__(512) void k_bnpool(const float* __restrict__ z,
                                                const float* __restrict__ ss,
                                                const int* __restrict__ gstart,
                                                unsigned short* __restrict__ hbf,
                                                float* __restrict__ out, int layer) {
    __shared__ float4 red[8][64];
    int g = blockIdx.x;
    int t = threadIdx.x;
    int q = t & 63, rg = t >> 6;
    float4 sc = ((const float4*)ss)[q];
    float4 sh = ((const float4*)(ss + DD))[q];
    int lo = gstart[g], hi = gstart[g + 1];
    float4 s = {0.f, 0.f, 0.f, 0.f};
    const float4* z4 = (const float4*)z;
    ushort4* h4 = (ushort4*)hbf;
    for (int r = lo + rg; r < hi; r += 8) {
        float4 v = z4[r * 64 + q];
        v.x = v.x * sc.x + sh.x;
        v.y = v.y * sc.y + sh.y;
        v.z = v.z * sc.z + sh.z;
        v.w = v.w * sc.w + sh.w;
        s.x += v.x; s.y += v.y; s.z += v.z; s.w += v.w;
        ushort4 o;
        o.x = f2bf(v.x); o.y = f2bf(v.y); o.z = f2bf(v.z); o.w = f2bf(v.w);
        h4[r * 64 + q] = o;
    }
    red[rg][q] = s;
    __syncthreads();
    if (rg < 4) {
        float4 a = red[rg][q], b = red[rg + 4][q];
        a.x += b.x; a.y += b.y; a.z += b.z; a.w += b.w;
        red[rg][q] = a;
    }
    __syncthreads();
    if (rg < 2) {
        float4 a = red[rg][q], b = red[rg + 2][q];
        a.x += b.x; a.y += b.y; a.z += b.z; a.w += b.w;
        red[rg][q] = a;
    }
    __syncthreads();
    if (rg == 0) {
        float4 a = red[0][q], b = red[1][q];
        a.x += b.x; a.y += b.y; a.z += b.z; a.w += b.w;
        ((float4*)(out + (size_t)g * (NL * DD) + layer * DD))[q] = a;
    }
}

extern "C" void kernel_launch(void* const* d_in, const int* in_sizes, int n_in,
                              void* d_out, int out_size, void* d_ws, size_t ws_size,
                              hipStream_t stream) {
    const float* x     = (const float*)d_in[0];
    const int*   ei    = (const int*)d_in[1];
    const int*   batch = (const int*)d_in[2];
    const float* w1    = (const float*)d_in[3];
    const float* b1    = (const float*)d_in[4];
    const float* w2    = (const float*)d_in[5];
    const float* b2    = (const float*)d_in[6];
    const float* gamma = (const float*)d_in[7];
    const float* beta  = (const float*)d_in[8];
    float* out = (float*)d_out;

    char* ws = (char*)d_ws;
    size_t off = 0;
    auto alloc = [&](size_t bytes) -> void* {
        void* p = ws + off;
        off += (bytes + 255) & ~size_t(255);
        return p;
    };
    float*          buf0 = (float*)alloc((size_t)MPAD * DD * 4);          // fp32 GEMM2 out
    unsigned short* zbf  = (unsigned short*)alloc((size_t)MPAD * DD * 2); // agg out (GEMM1 A)
    unsigned short* h1bf = (unsigned short*)alloc((size_t)MPAD * DD * 2); // GEMM1 out (GEMM2 A)
    unsigned short* hbf  = (unsigned short*)alloc((size_t)(NN + 64) * DD * 2); // h bf16 + sentinel row
    unsigned short* wt   = (unsigned short*)alloc((size_t)6 * DD * DD * 2);
    int* deg    = (int*)alloc((size_t)NN * 4);
    unsigned short* elist = (unsigned short*)alloc((size_t)NN * CAP * 2);
    int* gstart = (int*)alloc((size_t)(NG + 1) * 4);
    float* pstat = (float*)alloc((size_t)NMB * 512 * 4);
    float* ss   = (float*)alloc(2 * DD * 4);

    // CSR (one atomic pass) + graph boundaries (binary search)
    k_init<<<(NN + 255) / 256, 256, 0, stream>>>(deg);
    k_scatter<<<(NE + 255) / 256, 256, 0, stream>>>(ei, deg, elist);
    k_gbounds<<<1, 256, 0, stream>>>(batch, gstart);

    // weight transpose+convert, x -> bf16, sentinel row, zero pad rows of zbf
    k_wconv<<<(6 * 65536 + 255) / 256, 256, 0, stream>>>(w1, w2, wt);
    k_f2bf<<<(NN * DD / 4 + 255) / 256, 256, 0, stream>>>(x, hbf, NN * DD / 4);
    k_zrow<<<1, 256, 0, stream>>>(hbf);
    k_zpad<<<((MPAD - NN) * DD + 255) / 256, 256, 0, stream>>>(zbf);

    dim3 ggrid(MPAD / GBM, DD / GBM);
    for (int l = 0; l < NL; ++l) {
        k_agg_bf<<<NN / 4, 256, 0, stream>>>(hbf, deg, elist, zbf);
        k_mfma_gemm<1, 0><<<ggrid, 256, 0, stream>>>(zbf, wt + (size_t)l * DD * DD, b1 + l * DD, h1bf, nullptr);
        k_mfma_gemm<0, 1><<<ggrid, 256, 0, stream>>>(h1bf, wt + (size_t)(3 + l) * DD * DD, b2 + l * DD, buf0, pstat);
        k_bnscale2<<<DD, 256, 0, stream>>>(pstat, gamma + l * DD, beta + l * DD, ss);
        k_bnpool<<<NG, 512, 0, stream>>>(buf0, ss, gstart, hbf, out, l);
    }
}

// Round 9
// 419.855 us; speedup vs baseline: 1.0848x; 1.0723x over previous
//
#include <hip/hip_runtime.h>

#define NN 50000
#define NE 800000
#define NG 256
#define DD 256
#define NL 3
#define BN_EPS 1e-5f
#define MPAD 50048   // 391 * 128
#define CAP 96       // per-node edge bucket capacity (Poisson(16) tail @96 ~ 1e-40)
#define NMB 391      // MPAD / 128 (m-blocks)

typedef short bf16x8 __attribute__((ext_vector_type(8)));
typedef float f32x4 __attribute__((ext_vector_type(4)));
typedef unsigned short ushort8 __attribute__((ext_vector_type(8)));

__device__ __forceinline__ unsigned short f2bf(float f) {
    unsigned int u = __float_as_uint(f);
    u += 0x7FFFu + ((u >> 16) & 1u);
    return (unsigned short)(u >> 16);
}
__device__ __forceinline__ float bf2f(unsigned short s) {
    return __uint_as_float(((unsigned int)s) << 16);
}

// ---------- init: zero deg (doubles as scatter cursor) ----------
__global__ void k_init(int* __restrict__ deg) {
    int i = blockIdx.x * blockDim.x + threadIdx.x;
    if (i < NN) deg[i] = 0;
}

// one-pass CSR build: bucket scatter (u16 src); deg ends up as the in-degree
__global__ void k_scatter(const int* __restrict__ ei, int* __restrict__ deg,
                          unsigned short* __restrict__ elist) {
    int e = blockIdx.x * blockDim.x + threadIdx.x;
    if (e >= NE) return;
    int s = ei[e];          // src  (< 65536)
    int d = ei[NE + e];     // dst
    int pos = atomicAdd(&deg[d], 1);
    elist[(size_t)d * CAP + pos] = (unsigned short)s;
}

// graph boundaries via binary search over sorted batch
__global__ void k_gbounds(const int* __restrict__ batch, int* __restrict__ gstart) {
    int g = threadIdx.x;   // 0..255
    int lo = 0, hi = NN;
    while (lo < hi) {
        int mid = (lo + hi) >> 1;
        if (batch[mid] < g) lo = mid + 1; else hi = mid;
    }
    gstart[g] = lo;
    if (g == 0) gstart[NG] = NN;
}

// ---------- conversions ----------
__global__ void k_f2bf(const float* __restrict__ in, unsigned short* __restrict__ out, int n4) {
    int i = blockIdx.x * blockDim.x + threadIdx.x;
    if (i >= n4) return;
    float4 v = ((const float4*)in)[i];
    ushort4 o;
    o.x = f2bf(v.x); o.y = f2bf(v.y); o.z = f2bf(v.z); o.w = f2bf(v.w);
    ((ushort4*)out)[i] = o;
}

// zero the sentinel row (index NN) of hbf
__global__ void k_zrow(unsigned short* __restrict__ hbf) {
    hbf[(size_t)NN * DD + threadIdx.x] = 0;
}

__global__ void k_zpad(unsigned short* p) {
    int i = blockIdx.x * blockDim.x + threadIdx.x;
    const int total = (MPAD - NN) * DD;
    if (i < total) p[NN * DD + i] = 0;
}

// wt[mat][n][k] = w[mat][k][n] as bf16; mats 0..2 = w1 layers, 3..5 = w2 layers
__global__ void k_wconv(const float* __restrict__ w1, const float* __restrict__ w2,
                        unsigned short* __restrict__ wt) {
    int flat = blockIdx.x * blockDim.x + threadIdx.x;
    if (flat >= 6 * 65536) return;
    int mat = flat >> 16;
    int n = (flat >> 8) & 255;
    int k = flat & 255;
    const float* src = (mat < 3) ? (w1 + ((size_t)mat << 16)) : (w2 + ((size_t)(mat - 3) << 16));
    wt[flat] = f2bf(src[k * 256 + n]);
}

// ---------- aggregation (structural floor: compulsory per-XCD L2 misses) ----------
__global__ __launch_bounds__(256) void k_agg_bf(const unsigned short* __restrict__ h,
                                                const int* __restrict__ deg,
                                                const unsigned short* __restrict__ elist,
                                                unsigned short* __restrict__ z0) {
    int wave = threadIdx.x >> 6;
    int lane = threadIdx.x & 63;
    int node = blockIdx.x * 4 + wave;
    int chunk = lane & 31;
    int half = lane >> 5;
    const ushort8* h8 = (const ushort8*)h;

    float acc[8];
    if (half == 0) {
        ushort8 own = h8[(size_t)node * 32 + chunk];
        #pragma unroll
        for (int j = 0; j < 8; ++j) acc[j] = bf2f(own[j]);
    } else {
        #pragma unroll
        for (int j = 0; j < 8; ++j) acc[j] = 0.f;
    }

    int n = deg[node];
    const unsigned short* el = elist + (size_t)node * CAP;
    int i = 0;
    for (; i + 8 <= n; i += 8) {
        ushort8 sv = *(const ushort8*)(el + i);
        int i0 = half ? sv[1] : sv[0];
        int i1 = half ? sv[3] : sv[2];
        int i2 = half ? sv[5] : sv[4];
        int i3 = half ? sv[7] : sv[6];
        ushort8 r0 = h8[(size_t)i0 * 32 + chunk];
        ushort8 r1 = h8[(size_t)i1 * 32 + chunk];
        ushort8 r2 = h8[(size_t)i2 * 32 + chunk];
        ushort8 r3 = h8[(size_t)i3 * 32 + chunk];
        #pragma unroll
        for (int j = 0; j < 8; ++j) acc[j] += bf2f(r0[j]);
        #pragma unroll
        for (int j = 0; j < 8; ++j) acc[j] += bf2f(r1[j]);
        #pragma unroll
        for (int j = 0; j < 8; ++j) acc[j] += bf2f(r2[j]);
        #pragma unroll
        for (int j = 0; j < 8; ++j) acc[j] += bf2f(r3[j]);
    }
    for (; i < n; i += 2) {
        int s0 = el[i];
        int s1 = (i + 1 < n) ? (int)el[i + 1] : NN;
        int idx = half ? s1 : s0;
        ushort8 r = h8[(size_t)idx * 32 + chunk];
        #pragma unroll
        for (int j = 0; j < 8; ++j) acc[j] += bf2f(r[j]);
    }

    ushort8 o;
    #pragma unroll
    for (int j = 0; j < 8; ++j) {
        float other = __shfl_xor(acc[j], 32);
        o[j] = f2bf(acc[j] + other);
    }
    if (half == 0) ((ushort8*)z0)[(size_t)node * 32 + chunk] = o;
}

// ---------- fused MLP: relu(relu(z@W1+b1)@W2+b2) + BN partial stats ----------
// One block = 128 rows x full 256 cols. 8 waves (2x4). h1 lives in LDS (XOR-swizzled).
__global__ __launch_bounds__(512, 2) void k_mlp(const unsigned short* __restrict__ A,
                                                const unsigned short* __restrict__ BT1,
                                                const unsigned short* __restrict__ BT2,
                                                const float* __restrict__ b1,
                                                const float* __restrict__ b2,
                                                float* __restrict__ Cout,
                                                float* __restrict__ pstat) {
    __shared__ short As[128 * 64];     // z tile k-chunk
    __shared__ short Bs[256 * 64];     // W1T / W2T k-chunk (reused)
    __shared__ short H1[128 * 256];    // h1 tile, group-swizzled
    __shared__ float spart[2][256][2];
    int tid = threadIdx.x;
    int lane = tid & 63;
    int wave = tid >> 6;
    int wr = wave >> 2, wc = wave & 3;   // 2 x 4 waves, each 64x64
    long m0 = (long)blockIdx.x * 128;
    const int r = lane & 15, hi = lane >> 4;

    f32x4 acc[4][4];
    #pragma unroll
    for (int m = 0; m < 4; ++m)
        #pragma unroll
        for (int n = 0; n < 4; ++n)
            acc[m][n] = (f32x4){0.f, 0.f, 0.f, 0.f};

    // ---- GEMM1: h1 = relu(z @ W1 + b1) ----
    for (int k0 = 0; k0 < DD; k0 += 64) {
        #pragma unroll
        for (int p = 0; p < 2; ++p) {           // As: 1024 chunks
            int flat = p * 512 + tid;
            int row = flat >> 3, c8 = flat & 7;
            int slot = c8 ^ (row & 7);
            *(bf16x8*)(As + row * 64 + slot * 8) =
                *(const bf16x8*)(A + (m0 + row) * DD + k0 + c8 * 8);
        }
        #pragma unroll
        for (int p = 0; p < 4; ++p) {           // Bs: 2048 chunks (256 cols)
            int flat = p * 512 + tid;
            int row = flat >> 3, c8 = flat & 7;
            int slot = c8 ^ (row & 7);
            *(bf16x8*)(Bs + row * 64 + slot * 8) =
                *(const bf16x8*)(BT1 + (long)row * DD + k0 + c8 * 8);
        }
        __syncthreads();
        bf16x8 af[4][2], bfr[4][2];
        #pragma unroll
        for (int m = 0; m < 4; ++m) {
            int row = wr * 64 + m * 16 + r;
            #pragma unroll
            for (int kk = 0; kk < 2; ++kk) {
                int slot = (kk * 4 + hi) ^ (row & 7);
                af[m][kk] = *(const bf16x8*)(As + row * 64 + slot * 8);
            }
        }
        #pragma unroll
        for (int n = 0; n < 4; ++n) {
            int col = wc * 64 + n * 16 + r;
            #pragma unroll
            for (int kk = 0; kk < 2; ++kk) {
                int slot = (kk * 4 + hi) ^ (col & 7);
                bfr[n][kk] = *(const bf16x8*)(Bs + col * 64 + slot * 8);
            }
        }
        #pragma unroll
        for (int kk = 0; kk < 2; ++kk)
            #pragma unroll
            for (int m = 0; m < 4; ++m)
                #pragma unroll
                for (int n = 0; n < 4; ++n)
                    acc[m][n] = __builtin_amdgcn_mfma_f32_16x16x32_bf16(af[m][kk], bfr[n][kk], acc[m][n], 0, 0, 0);
        __syncthreads();
    }

    // h1 epilogue -> LDS (group-swizzled: group g of 8 elems stored at g^(row&7))
    #pragma unroll
    for (int n = 0; n < 4; ++n) {
        int col = wc * 64 + n * 16 + r;
        float bv = b1[col];
        int g = col >> 3, j8 = col & 7;
        #pragma unroll
        for (int m = 0; m < 4; ++m) {
            #pragma unroll
            for (int j = 0; j < 4; ++j) {
                int row = wr * 64 + m * 16 + hi * 4 + j;
                float v = acc[m][n][j] + bv;
                v = v > 0.f ? v : 0.f;
                H1[row * 256 + (g ^ (row & 7)) * 8 + j8] = (short)f2bf(v);
            }
        }
    }
    #pragma unroll
    for (int m = 0; m < 4; ++m)
        #pragma unroll
        for (int n = 0; n < 4; ++n)
            acc[m][n] = (f32x4){0.f, 0.f, 0.f, 0.f};
    __syncthreads();

    // ---- GEMM2: y = relu(h1 @ W2 + b2) ----
    for (int k0 = 0; k0 < DD; k0 += 64) {
        #pragma unroll
        for (int p = 0; p < 4; ++p) {
            int flat = p * 512 + tid;
            int row = flat >> 3, c8 = flat & 7;
            int slot = c8 ^ (row & 7);
            *(bf16x8*)(Bs + row * 64 + slot * 8) =
                *(const bf16x8*)(BT2 + (long)row * DD + k0 + c8 * 8);
        }
        __syncthreads();
        bf16x8 af[4][2], bfr[4][2];
        #pragma unroll
        for (int m = 0; m < 4; ++m) {
            int row = wr * 64 + m * 16 + r;
            #pragma unroll
            for (int kk = 0; kk < 2; ++kk) {
                int g = (k0 >> 3) + kk * 4 + hi;
                af[m][kk] = *(const bf16x8*)(H1 + row * 256 + (g ^ (row & 7)) * 8);
            }
        }
        #pragma unroll
        for (int n = 0; n < 4; ++n) {
            int col = wc * 64 + n * 16 + r;
            #pragma unroll
            for (int kk = 0; kk < 2; ++kk) {
                int slot = (kk * 4 + hi) ^ (col & 7);
                bfr[n][kk] = *(const bf16x8*)(Bs + col * 64 + slot * 8);
            }
        }
        #pragma unroll
        for (int kk = 0; kk < 2; ++kk)
            #pragma unroll
            for (int m = 0; m < 4; ++m)
                #pragma unroll
                for (int n = 0; n < 4; ++n)
                    acc[m][n] = __builtin_amdgcn_mfma_f32_16x16x32_bf16(af[m][kk], bfr[n][kk], acc[m][n], 0, 0, 0);
        __syncthreads();
    }

    // epilogue: bias + relu -> fp32 out, fused BN column partials
    #pragma unroll
    for (int n = 0; n < 4; ++n) {
        int col = wc * 64 + n * 16 + r;
        float bv = b2[col];
        float cs = 0.f, cs2 = 0.f;
        #pragma unroll
        for (int m = 0; m < 4; ++m) {
            #pragma unroll
            for (int j = 0; j < 4; ++j) {
                long grow = m0 + wr * 64 + m * 16 + hi * 4 + j;
                float v = acc[m][n][j] + bv;
                v = v > 0.f ? v : 0.f;
                Cout[grow * DD + col] = v;
                float vm = (grow < NN) ? v : 0.f;
                cs += vm; cs2 += vm * vm;
            }
        }
        cs  += __shfl_xor(cs, 16);  cs  += __shfl_xor(cs, 32);
        cs2 += __shfl_xor(cs2, 16); cs2 += __shfl_xor(cs2, 32);
        if (hi == 0) {
            spart[wr][col][0] = cs;
            spart[wr][col][1] = cs2;
        }
    }
    __syncthreads();
    if (tid < 256) {
        float s  = spart[0][tid][0] + spart[1][tid][0];
        float s2 = spart[0][tid][1] + spart[1][tid][1];
        pstat[(size_t)blockIdx.x * 512 + tid] = s;
        pstat[(size_t)blockIdx.x * 512 + 256 + tid] = s2;
    }
}

// reduce per-block partials -> BN scale/shift (one block per column, fixed tree)
__global__ __launch_bounds__(256) void k_bnscale2(const float* __restrict__ pstat,
                                                  const float* __restrict__ gamma,
                                                  const float* __restrict__ beta,
                                                  float* __restrict__ ss) {
    int c = blockIdx.x;
    int t = threadIdx.x;
    float s = 0.f, s2 = 0.f;
    for (int mb = t; mb < NMB; mb += 256) {
        s  += pstat[(size_t)mb * 512 + c];
        s2 += pstat[(size_t)mb * 512 + 256 + c];
    }
    __shared__ float rs[256], rs2[256];
    rs[t] = s; rs2[t] = s2;
    __syncthreads();
    #pragma unroll
    for (int d = 128; d > 0; d >>= 1) {
        if (t < d) { rs[t] += rs[t + d]; rs2[t] += rs2[t + d]; }
        __syncthreads();
    }
    if (t == 0) {
        float mean = rs[0] * (1.0f / NN);
        float var = rs2[0] * (1.0f / NN) - mean * mean;
        float sc = gamma[c] * rsqrtf(var + BN_EPS);
        ss[c] = sc;
        ss[DD + c] = beta[c] - mean * sc;
    }
}

// fused BN-apply + bf16 emit + global_add_pool; 512 thr: quad q (64) x rowgroup rg (8)
__global__ __launch_bounds__(512) void k_bnpool(const float* __restrict__ z,
                                                const float* __restrict__ ss,
                                                const int* __restrict__ gstart,
                                                unsigned short* __restrict__ hbf,
                                                float* __restrict__ out, int layer) {
    __shared__ float4 red[8][64];
    int g = blockIdx.x;
    int t = threadIdx.x;
    int q = t & 63, rg = t >> 6;
    float4 sc = ((const float4*)ss)[q];
    float4 sh = ((const float4*)(ss + DD))[q];
    int lo = gstart[g], hi = gstart[g + 1];
    float4 s = {0.f, 0.f, 0.f, 0.f};
    const float4* z4 = (const float4*)z;
    ushort4* h4 = (ushort4*)hbf;
    for (int r = lo + rg; r < hi; r += 8) {
        float4 v = z4[r * 64 + q];
        v.x = v.x * sc.x + sh.x;
        v.y = v.y * sc.y + sh.y;
        v.z = v.z * sc.z + sh.z;
        v.w = v.w * sc.w + sh.w;
        s.x += v.x; s.y += v.y; s.z += v.z; s.w += v.w;
        ushort4 o;
        o.x = f2bf(v.x); o.y = f2bf(v.y); o.z = f2bf(v.z); o.w = f2bf(v.w);
        h4[r * 64 + q] = o;
    }
    red[rg][q] = s;
    __syncthreads();
    if (rg < 4) {
        float4 a = red[rg][q], b = red[rg + 4][q];
        a.x += b.x; a.y += b.y; a.z += b.z; a.w += b.w;
        red[rg][q] = a;
    }
    __syncthreads();
    if (rg < 2) {
        float4 a = red[rg][q], b = red[rg + 2][q];
        a.x += b.x; a.y += b.y; a.z += b.z; a.w += b.w;
        red[rg][q] = a;
    }
    __syncthreads();
    if (rg == 0) {
        float4 a = red[0][q], b = red[1][q];
        a.x += b.x; a.y += b.y; a.z += b.z; a.w += b.w;
        ((float4*)(out + (size_t)g * (NL * DD) + layer * DD))[q] = a;
    }
}

extern "C" void kernel_launch(void* const* d_in, const int* in_sizes, int n_in,
                              void* d_out, int out_size, void* d_ws, size_t ws_size,
                              hipStream_t stream) {
    const float* x     = (const float*)d_in[0];
    const int*   ei    = (const int*)d_in[1];
    const int*   batch = (const int*)d_in[2];
    const float* w1    = (const float*)d_in[3];
    const float* b1    = (const float*)d_in[4];
    const float* w2    = (const float*)d_in[5];
    const float* b2    = (const float*)d_in[6];
    const float* gamma = (const float*)d_in[7];
    const float* beta  = (const float*)d_in[8];
    float* out = (float*)d_out;

    char* ws = (char*)d_ws;
    size_t off = 0;
    auto alloc = [&](size_t bytes) -> void* {
        void* p = ws + off;
        off += (bytes + 255) & ~size_t(255);
        return p;
    };
    float*          buf0 = (float*)alloc((size_t)MPAD * DD * 4);          // fp32 MLP out
    unsigned short* zbf  = (unsigned short*)alloc((size_t)MPAD * DD * 2); // agg out (MLP A)
    unsigned short* hbf  = (unsigned short*)alloc((size_t)(NN + 64) * DD * 2); // h bf16 + sentinel row
    unsigned short* wt   = (unsigned short*)alloc((size_t)6 * DD * DD * 2);
    int* deg    = (int*)alloc((size_t)NN * 4);
    unsigned short* elist = (unsigned short*)alloc((size_t)NN * CAP * 2);
    int* gstart = (int*)alloc((size_t)(NG + 1) * 4);
    float* pstat = (float*)alloc((size_t)NMB * 512 * 4);
    float* ss   = (float*)alloc(2 * DD * 4);

    // CSR (one atomic pass) + graph boundaries (binary search)
    k_init<<<(NN + 255) / 256, 256, 0, stream>>>(deg);
    k_scatter<<<(NE + 255) / 256, 256, 0, stream>>>(ei, deg, elist);
    k_gbounds<<<1, 256, 0, stream>>>(batch, gstart);

    // weight transpose+convert, x -> bf16, sentinel row, zero pad rows of zbf
    k_wconv<<<(6 * 65536 + 255) / 256, 256, 0, stream>>>(w1, w2, wt);
    k_f2bf<<<(NN * DD / 4 + 255) / 256, 256, 0, stream>>>(x, hbf, NN * DD / 4);
    k_zrow<<<1, 256, 0, stream>>>(hbf);
    k_zpad<<<((MPAD - NN) * DD + 255) / 256, 256, 0, stream>>>(zbf);

    for (int l = 0; l < NL; ++l) {
        k_agg_bf<<<NN / 4, 256, 0, stream>>>(hbf, deg, elist, zbf);
        k_mlp<<<NMB, 512, 0, stream>>>(zbf, wt + (size_t)l * DD * DD,
                                       wt + (size_t)(3 + l) * DD * DD,
                                       b1 + l * DD, b2 + l * DD, buf0, pstat);
        k_bnscale2<<<DD, 256, 0, stream>>>(pstat, gamma + l * DD, beta + l * DD, ss);
        k_bnpool<<<NG, 512, 0, stream>>>(buf0, ss, gstart, hbf, out, l);
    }
}

// Round 10
// 416.516 us; speedup vs baseline: 1.0935x; 1.0080x over previous
//
#include <hip/hip_runtime.h>

#define NN 50000
#define NE 800000
#define NG 256
#define DD 256
#define NL 3
#define BN_EPS 1e-5f
#define MPAD 50048   // 391 * 128
#define CAP 96       // per-node edge bucket capacity (Poisson(16) tail @96 ~ 1e-40)
#define NMB 391      // MPAD / 128 (m-blocks)

typedef short bf16x8 __attribute__((ext_vector_type(8)));
typedef float f32x4 __attribute__((ext_vector_type(4)));
typedef unsigned short ushort8 __attribute__((ext_vector_type(8)));

__device__ __forceinline__ unsigned short f2bf(float f) {
    unsigned int u = __float_as_uint(f);
    u += 0x7FFFu + ((u >> 16) & 1u);
    return (unsigned short)(u >> 16);
}
__device__ __forceinline__ float bf2f(unsigned short s) {
    return __uint_as_float(((unsigned int)s) << 16);
}

// ---------- fused setup: f2bf(x), wconv, deg=0, zpad, zrow, gbounds ----------
#define R0 3200000          // f2bf float4 groups (NN*DD/4)
#define R1 393216           // wconv elems (6*65536)
#define R2 50000            // deg zero
#define R3 12288            // zpad elems ((MPAD-NN)*DD)
#define R4 256              // zrow (sentinel row)
#define R5 256              // gbounds
#define RTOT (R0 + R1 + R2 + R3 + R4 + R5)

__global__ void k_setup(const float* __restrict__ x, const float* __restrict__ w1,
                        const float* __restrict__ w2, const int* __restrict__ batch,
                        unsigned short* __restrict__ hbf, unsigned short* __restrict__ wt,
                        int* __restrict__ deg, unsigned short* __restrict__ zbf,
                        int* __restrict__ gstart) {
    int i = blockIdx.x * blockDim.x + threadIdx.x;
    if (i < R0) {
        float4 v = ((const float4*)x)[i];
        ushort4 o;
        o.x = f2bf(v.x); o.y = f2bf(v.y); o.z = f2bf(v.z); o.w = f2bf(v.w);
        ((ushort4*)hbf)[i] = o;
        return;
    }
    i -= R0;
    if (i < R1) {
        int mat = i >> 16;
        int n = (i >> 8) & 255;
        int k = i & 255;
        const float* src = (mat < 3) ? (w1 + ((size_t)mat << 16)) : (w2 + ((size_t)(mat - 3) << 16));
        wt[i] = f2bf(src[k * 256 + n]);
        return;
    }
    i -= R1;
    if (i < R2) { deg[i] = 0; return; }
    i -= R2;
    if (i < R3) { zbf[NN * DD + i] = 0; return; }
    i -= R3;
    if (i < R4) { hbf[(size_t)NN * DD + i] = 0; return; }
    i -= R4;
    if (i < R5) {
        int g = i;
        int lo = 0, hi = NN;
        while (lo < hi) {
            int mid = (lo + hi) >> 1;
            if (batch[mid] < g) lo = mid + 1; else hi = mid;
        }
        gstart[g] = lo;
        if (g == 0) gstart[NG] = NN;
    }
}

// one-pass CSR build: bucket scatter (u16 src); deg ends up as the in-degree
__global__ void k_scatter(const int* __restrict__ ei, int* __restrict__ deg,
                          unsigned short* __restrict__ elist) {
    int e = blockIdx.x * blockDim.x + threadIdx.x;
    if (e >= NE) return;
    int s = ei[e];          // src  (< 65536)
    int d = ei[NE + e];     // dst
    int pos = atomicAdd(&deg[d], 1);
    elist[(size_t)d * CAP + pos] = (unsigned short)s;
}

// ---------- aggregation: half-feature pass (halves concurrent L2 footprint) ----------
// 16 lanes x 16B = 256B half-row; 4 edge-ways per wave (4 rows per VMEM instr).
template<int HALF>
__global__ __launch_bounds__(256) void k_agg_bf(const unsigned short* __restrict__ h,
                                                const int* __restrict__ deg,
                                                const unsigned short* __restrict__ elist,
                                                unsigned short* __restrict__ z0) {
    int wave = threadIdx.x >> 6;
    int lane = threadIdx.x & 63;
    int node = blockIdx.x * 4 + wave;
    int chunk = lane & 15;
    int eway = lane >> 4;               // 0..3
    const int base = HALF * 16 + chunk;
    const ushort8* h8 = (const ushort8*)h;

    float acc[8];
    if (eway == 0) {
        ushort8 own = h8[(size_t)node * 32 + base];
        #pragma unroll
        for (int j = 0; j < 8; ++j) acc[j] = bf2f(own[j]);
    } else {
        #pragma unroll
        for (int j = 0; j < 8; ++j) acc[j] = 0.f;
    }

    int n = deg[node];
    const unsigned short* el = elist + (size_t)node * CAP;
    int i = 0;
    for (; i + 8 <= n; i += 8) {
        ushort8 sv = *(const ushort8*)(el + i);
        int i0 = sv[eway];
        int i1 = sv[eway + 4];
        ushort8 r0 = h8[(size_t)i0 * 32 + base];
        ushort8 r1 = h8[(size_t)i1 * 32 + base];
        #pragma unroll
        for (int j = 0; j < 8; ++j) acc[j] += bf2f(r0[j]);
        #pragma unroll
        for (int j = 0; j < 8; ++j) acc[j] += bf2f(r1[j]);
    }
    for (; i < n; i += 4) {
        int e = i + eway;
        int idx = (e < n) ? (int)el[e] : NN;   // sentinel zero row
        ushort8 r = h8[(size_t)idx * 32 + base];
        #pragma unroll
        for (int j = 0; j < 8; ++j) acc[j] += bf2f(r[j]);
    }

    ushort8 o;
    #pragma unroll
    for (int j = 0; j < 8; ++j) {
        float v = acc[j];
        v += __shfl_xor(v, 16);
        v += __shfl_xor(v, 32);
        o[j] = f2bf(v);
    }
    if (eway == 0) ((ushort8*)z0)[(size_t)node * 32 + base] = o;
}

// ---------- fused MLP: relu(relu(z@W1+b1)@W2+b2) + BN partial stats ----------
__global__ __launch_bounds__(512, 2) void k_mlp(const unsigned short* __restrict__ A,
                                                const unsigned short* __restrict__ BT1,
                                                const unsigned short* __restrict__ BT2,
                                                const float* __restrict__ b1,
                                                const float* __restrict__ b2,
                                                float* __restrict__ Cout,
                                                float* __restrict__ pstat) {
    __shared__ short As[128 * 64];
    __shared__ short Bs[256 * 64];
    __shared__ short H1[128 * 256];
    __shared__ float spart[2][256][2];
    int tid = threadIdx.x;
    int lane = tid & 63;
    int wave = tid >> 6;
    int wr = wave >> 2, wc = wave & 3;
    long m0 = (long)blockIdx.x * 128;
    const int r = lane & 15, hi = lane >> 4;

    f32x4 acc[4][4];
    #pragma unroll
    for (int m = 0; m < 4; ++m)
        #pragma unroll
        for (int n = 0; n < 4; ++n)
            acc[m][n] = (f32x4){0.f, 0.f, 0.f, 0.f};

    for (int k0 = 0; k0 < DD; k0 += 64) {
        #pragma unroll
        for (int p = 0; p < 2; ++p) {
            int flat = p * 512 + tid;
            int row = flat >> 3, c8 = flat & 7;
            int slot = c8 ^ (row & 7);
            *(bf16x8*)(As + row * 64 + slot * 8) =
                *(const bf16x8*)(A + (m0 + row) * DD + k0 + c8 * 8);
        }
        #pragma unroll
        for (int p = 0; p < 4; ++p) {
            int flat = p * 512 + tid;
            int row = flat >> 3, c8 = flat & 7;
            int slot = c8 ^ (row & 7);
            *(bf16x8*)(Bs + row * 64 + slot * 8) =
                *(const bf16x8*)(BT1 + (long)row * DD + k0 + c8 * 8);
        }
        __syncthreads();
        bf16x8 af[4][2], bfr[4][2];
        #pragma unroll
        for (int m = 0; m < 4; ++m) {
            int row = wr * 64 + m * 16 + r;
            #pragma unroll
            for (int kk = 0; kk < 2; ++kk) {
                int slot = (kk * 4 + hi) ^ (row & 7);
                af[m][kk] = *(const bf16x8*)(As + row * 64 + slot * 8);
            }
        }
        #pragma unroll
        for (int n = 0; n < 4; ++n) {
            int col = wc * 64 + n * 16 + r;
            #pragma unroll
            for (int kk = 0; kk < 2; ++kk) {
                int slot = (kk * 4 + hi) ^ (col & 7);
                bfr[n][kk] = *(const bf16x8*)(Bs + col * 64 + slot * 8);
            }
        }
        #pragma unroll
        for (int kk = 0; kk < 2; ++kk)
            #pragma unroll
            for (int m = 0; m < 4; ++m)
                #pragma unroll
                for (int n = 0; n < 4; ++n)
                    acc[m][n] = __builtin_amdgcn_mfma_f32_16x16x32_bf16(af[m][kk], bfr[n][kk], acc[m][n], 0, 0, 0);
        __syncthreads();
    }

    #pragma unroll
    for (int n = 0; n < 4; ++n) {
        int col = wc * 64 + n * 16 + r;
        float bv = b1[col];
        int g = col >> 3, j8 = col & 7;
        #pragma unroll
        for (int m = 0; m < 4; ++m) {
            #pragma unroll
            for (int j = 0; j < 4; ++j) {
                int row = wr * 64 + m * 16 + hi * 4 + j;
                float v = acc[m][n][j] + bv;
                v = v > 0.f ? v : 0.f;
                H1[row * 256 + (g ^ (row & 7)) * 8 + j8] = (short)f2bf(v);
            }
        }
    }
    #pragma unroll
    for (int m = 0; m < 4; ++m)
        #pragma unroll
        for (int n = 0; n < 4; ++n)
            acc[m][n] = (f32x4){0.f, 0.f, 0.f, 0.f};
    __syncthreads();

    for (int k0 = 0; k0 < DD; k0 += 64) {
        #pragma unroll
        for (int p = 0; p < 4; ++p) {
            int flat = p * 512 + tid;
            int row = flat >> 3, c8 = flat & 7;
            int slot = c8 ^ (row & 7);
            *(bf16x8*)(Bs + row * 64 + slot * 8) =
                *(const bf16x8*)(BT2 + (long)row * DD + k0 + c8 * 8);
        }
        __syncthreads();
        bf16x8 af[4][2], bfr[4][2];
        #pragma unroll
        for (int m = 0; m < 4; ++m) {
            int row = wr * 64 + m * 16 + r;
            #pragma unroll
            for (int kk = 0; kk < 2; ++kk) {
                int g = (k0 >> 3) + kk * 4 + hi;
                af[m][kk] = *(const bf16x8*)(H1 + row * 256 + (g ^ (row & 7)) * 8);
            }
        }
        #pragma unroll
        for (int n = 0; n < 4; ++n) {
            int col = wc * 64 + n * 16 + r;
            #pragma unroll
            for (int kk = 0; kk < 2; ++kk) {
                int slot = (kk * 4 + hi) ^ (col & 7);
                bfr[n][kk] = *(const bf16x8*)(Bs + col * 64 + slot * 8);
            }
        }
        #pragma unroll
        for (int kk = 0; kk < 2; ++kk)
            #pragma unroll
            for (int m = 0; m < 4; ++m)
                #pragma unroll
                for (int n = 0; n < 4; ++n)
                    acc[m][n] = __builtin_amdgcn_mfma_f32_16x16x32_bf16(af[m][kk], bfr[n][kk], acc[m][n], 0, 0, 0);
        __syncthreads();
    }

    #pragma unroll
    for (int n = 0; n < 4; ++n) {
        int col = wc * 64 + n * 16 + r;
        float bv = b2[col];
        float cs = 0.f, cs2 = 0.f;
        #pragma unroll
        for (int m = 0; m < 4; ++m) {
            #pragma unroll
            for (int j = 0; j < 4; ++j) {
                long grow = m0 + wr * 64 + m * 16 + hi * 4 + j;
                float v = acc[m][n][j] + bv;
                v = v > 0.f ? v : 0.f;
                Cout[grow * DD + col] = v;
                float vm = (grow < NN) ? v : 0.f;
                cs += vm; cs2 += vm * vm;
            }
        }
        cs  += __shfl_xor(cs, 16);  cs  += __shfl_xor(cs, 32);
        cs2 += __shfl_xor(cs2, 16); cs2 += __shfl_xor(cs2, 32);
        if (hi == 0) {
            spart[wr][col][0] = cs;
            spart[wr][col][1] = cs2;
        }
    }
    __syncthreads();
    if (tid < 256) {
        float s  = spart[0][tid][0] + spart[1][tid][0];
        float s2 = spart[0][tid][1] + spart[1][tid][1];
        pstat[(size_t)blockIdx.x * 512 + tid] = s;
        pstat[(size_t)blockIdx.x * 512 + 256 + tid] = s2;
    }
}

// reduce per-block partials -> BN scale/shift (one block per column, fixed tree)
__global__ __launch_bounds__(256) void k_bnscale2(const float* __restrict__ pstat,
                                                  const float* __restrict__ gamma,
                                                  const float* __restrict__ beta,
                                                  float* __restrict__ ss) {
    int c = blockIdx.x;
    int t = threadIdx.x;
    float s = 0.f, s2 = 0.f;
    for (int mb = t; mb < NMB; mb += 256) {
        s  += pstat[(size_t)mb * 512 + c];
        s2 += pstat[(size_t)mb * 512 + 256 + c];
    }
    __shared__ float rs[256], rs2[256];
    rs[t] = s; rs2[t] = s2;
    __syncthreads();
    #pragma unroll
    for (int d = 128; d > 0; d >>= 1) {
        if (t < d) { rs[t] += rs[t + d]; rs2[t] += rs2[t + d]; }
        __syncthreads();
    }
    if (t == 0) {
        float mean = rs[0] * (1.0f / NN);
        float var = rs2[0] * (1.0f / NN) - mean * mean;
        float sc = gamma[c] * rsqrtf(var + BN_EPS);
        ss[c] = sc;
        ss[DD + c] = beta[c] - mean * sc;
    }
}

// fused BN-apply + bf16 emit + pool; grid (NG, 2): col-half per blockIdx.y.
// 512 thr: quad q (32 float4 = 128 cols) x rowgroup rg (16). LAST skips hbf store.
template<int LAST>
__global__ __launch_bounds__(512) void k_bnpool(const float* __restrict__ z,
                                                const float* __restrict__ ss,
                                                const int* __restrict__ gstart,
                                                unsigned short* __restrict__ hbf,
                                                float* __restrict__ out, int layer) {
    __shared__ float4 red[16][32];
    int g = blockIdx.x;
    int ch = blockIdx.y;
    int t = threadIdx.x;
    int q = t & 31, rg = t >> 5;
    int cq = ch * 32 + q;
    float4 sc = ((const float4*)ss)[cq];
    float4 sh = ((const float4*)(ss + DD))[cq];
    int lo = gstart[g], hi = gstart[g + 1];
    float4 s = {0.f, 0.f, 0.f, 0.f};
    const float4* z4 = (const float4*)z;
    ushort4* h4 = (ushort4*)hbf;
    for (int r = lo + rg; r < hi; r += 16) {
        float4 v = z4[(size_t)r * 64 + cq];
        v.x = v.x * sc.x + sh.x;
        v.y = v.y * sc.y + sh.y;
        v.z = v.z * sc.z + sh.z;
        v.w = v.w * sc.w + sh.w;
        s.x += v.x; s.y += v.y; s.z += v.z; s.w += v.w;
        if (!LAST) {
            ushort4 o;
            o.x = f2bf(v.x); o.y = f2bf(v.y); o.z = f2bf(v.z); o.w = f2bf(v.w);
            h4[(size_t)r * 64 + cq] = o;
        }
    }
    red[rg][q] = s;
    __syncthreads();
    #pragma unroll
    for (int d = 8; d > 0; d >>= 1) {
        if (rg < d) {
            float4 a = red[rg][q], b = red[rg + d][q];
            a.x += b.x; a.y += b.y; a.z += b.z; a.w += b.w;
            red[rg][q] = a;
        }
        __syncthreads();
    }
    if (rg == 0) {
        ((float4*)(out + (size_t)g * (NL * DD) + layer * DD))[cq] = red[0][q];
    }
}

extern "C" void kernel_launch(void* const* d_in, const int* in_sizes, int n_in,
                              void* d_out, int out_size, void* d_ws, size_t ws_size,
                              hipStream_t stream) {
    const float* x     = (const float*)d_in[0];
    const int*   ei    = (const int*)d_in[1];
    const int*   batch = (const int*)d_in[2];
    const float* w1    = (const float*)d_in[3];
    const float* b1    = (const float*)d_in[4];
    const float* w2    = (const float*)d_in[5];
    const float* b2    = (const float*)d_in[6];
    const float* gamma = (const float*)d_in[7];
    const float* beta  = (const float*)d_in[8];
    float* out = (float*)d_out;

    char* ws = (char*)d_ws;
    size_t off = 0;
    auto alloc = [&](size_t bytes) -> void* {
        void* p = ws + off;
        off += (bytes + 255) & ~size_t(255);
        return p;
    };
    float*          buf0 = (float*)alloc((size_t)MPAD * DD * 4);                 // fp32 MLP out
    unsigned short* zbf  = (unsigned short*)alloc((size_t)MPAD * DD * 2);        // agg out (MLP A)
    unsigned short* hbf  = (unsigned short*)alloc((size_t)(NN + 64) * DD * 2);   // h bf16 + sentinel
    unsigned short* wt   = (unsigned short*)alloc((size_t)6 * DD * DD * 2);
    int* deg    = (int*)alloc((size_t)NN * 4);
    unsigned short* elist = (unsigned short*)alloc((size_t)NN * CAP * 2);
    int* gstart = (int*)alloc((size_t)(NG + 1) * 4);
    float* pstat = (float*)alloc((size_t)NMB * 512 * 4);
    float* ss   = (float*)alloc(2 * DD * 4);

    k_setup<<<(RTOT + 255) / 256, 256, 0, stream>>>(x, w1, w2, batch, hbf, wt, deg, zbf, gstart);
    k_scatter<<<(NE + 255) / 256, 256, 0, stream>>>(ei, deg, elist);

    for (int l = 0; l < NL; ++l) {
        k_agg_bf<0><<<NN / 4, 256, 0, stream>>>(hbf, deg, elist, zbf);
        k_agg_bf<1><<<NN / 4, 256, 0, stream>>>(hbf, deg, elist, zbf);
        k_mlp<<<NMB, 512, 0, stream>>>(zbf, wt + (size_t)l * DD * DD,
                                       wt + (size_t)(3 + l) * DD * DD,
                                       b1 + l * DD, b2 + l * DD, buf0, pstat);
        k_bnscale2<<<DD, 256, 0, stream>>>(pstat, gamma + l * DD, beta + l * DD, ss);
        if (l < NL - 1)
            k_bnpool<0><<<dim3(NG, 2), 512, 0, stream>>>(buf0, ss, gstart, hbf, out, l);
        else
            k_bnpool<1><<<dim3(NG, 2), 512, 0, stream>>>(buf0, ss, gstart, hbf, out, l);
    }
}

// Round 11
// 395.353 us; speedup vs baseline: 1.1520x; 1.0535x over previous
//
#include <hip/hip_runtime.h>

#define NN 50000
#define NE 800000
#define NG 256
#define DD 256
#define NL 3
#define BN_EPS 1e-5f
#define MPAD 50048   // 391 * 128
#define CAP 96       // per-node edge bucket capacity
#define NMB 391      // MPAD / 128 (m-blocks)
#define NBIN 196     // ceil(NN/256) dst bins

typedef short bf16x8 __attribute__((ext_vector_type(8)));
typedef float f32x4 __attribute__((ext_vector_type(4)));
typedef unsigned short ushort8 __attribute__((ext_vector_type(8)));

__device__ __forceinline__ unsigned short f2bf(float f) {
    unsigned int u = __float_as_uint(f);
    u += 0x7FFFu + ((u >> 16) & 1u);
    return (unsigned short)(u >> 16);
}
__device__ __forceinline__ float bf2f(unsigned short s) {
    return __uint_as_float(((unsigned int)s) << 16);
}

// ---------- fused setup: f2bf(x), wconv, zpad, zrow, gbounds, bin_cnt=0 ----------
#define R0 3200000          // f2bf float4 groups (NN*DD/4)
#define R1 393216           // wconv elems (6*65536)
#define R2 12288            // zpad elems ((MPAD-NN)*DD)
#define R3 256              // zrow (sentinel row)
#define R4 256              // gbounds
#define R5 NBIN             // bin_cnt zero
#define RTOT (R0 + R1 + R2 + R3 + R4 + R5)

__global__ void k_setup(const float* __restrict__ x, const float* __restrict__ w1,
                        const float* __restrict__ w2, const int* __restrict__ batch,
                        unsigned short* __restrict__ hbf, unsigned short* __restrict__ wt,
                        unsigned short* __restrict__ zbf, int* __restrict__ gstart,
                        int* __restrict__ bin_cnt) {
    int i = blockIdx.x * blockDim.x + threadIdx.x;
    if (i < R0) {
        float4 v = ((const float4*)x)[i];
        ushort4 o;
        o.x = f2bf(v.x); o.y = f2bf(v.y); o.z = f2bf(v.z); o.w = f2bf(v.w);
        ((ushort4*)hbf)[i] = o;
        return;
    }
    i -= R0;
    if (i < R1) {
        int mat = i >> 16;
        int n = (i >> 8) & 255;
        int k = i & 255;
        const float* src = (mat < 3) ? (w1 + ((size_t)mat << 16)) : (w2 + ((size_t)(mat - 3) << 16));
        wt[i] = f2bf(src[k * 256 + n]);
        return;
    }
    i -= R1;
    if (i < R2) { zbf[NN * DD + i] = 0; return; }
    i -= R2;
    if (i < R3) { hbf[(size_t)NN * DD + i] = 0; return; }
    i -= R3;
    if (i < R4) {
        int g = i;
        int lo = 0, hi = NN;
        while (lo < hi) {
            int mid = (lo + hi) >> 1;
            if (batch[mid] < g) lo = mid + 1; else hi = mid;
        }
        gstart[g] = lo;
        if (g == 0) gstart[NG] = NN;
        return;
    }
    i -= R4;
    if (i < R5) bin_cnt[i] = 0;
}

// ---------- binned CSR build (kills dirty-line write amplification) ----------
// phase 1: per-bin edge counts (LDS histogram, 1 global atomic per bin per block)
__global__ __launch_bounds__(256) void k_bin1(const int* __restrict__ ei,
                                              int* __restrict__ bin_cnt) {
    __shared__ int hist[NBIN];
    int t = threadIdx.x;
    for (int i = t; i < NBIN; i += 256) hist[i] = 0;
    __syncthreads();
    #pragma unroll
    for (int j = 0; j < 4; ++j) {
        int e = blockIdx.x * 1024 + j * 256 + t;
        if (e < NE) atomicAdd(&hist[ei[NE + e] >> 8], 1);
    }
    __syncthreads();
    for (int i = t; i < NBIN; i += 256)
        if (hist[i]) atomicAdd(&bin_cnt[i], hist[i]);
}

// phase 1b: exclusive scan of bin counts
__global__ void k_binscan(const int* __restrict__ bin_cnt, int* __restrict__ bin_start,
                          int* __restrict__ bin_cursor) {
    __shared__ int s[256];
    int t = threadIdx.x;
    int v = (t < NBIN) ? bin_cnt[t] : 0;
    s[t] = v;
    __syncthreads();
    #pragma unroll
    for (int d = 1; d < 256; d <<= 1) {
        int a = (t >= d) ? s[t - d] : 0;
        __syncthreads();
        s[t] += a;
        __syncthreads();
    }
    int excl = s[t] - v;
    if (t < NBIN) { bin_start[t] = excl; bin_cursor[t] = excl; }
    if (t == 0) bin_start[NBIN] = NE;
}

// phase 2: scatter packed (src, d&255) records into contiguous bin segments
__global__ __launch_bounds__(256) void k_bin2(const int* __restrict__ ei,
                                              int* __restrict__ bin_cursor,
                                              unsigned int* __restrict__ binbuf) {
    __shared__ int hist[NBIN], base[NBIN], lcur[NBIN];
    int t = threadIdx.x;
    for (int i = t; i < NBIN; i += 256) { hist[i] = 0; lcur[i] = 0; }
    __syncthreads();
    int d[4], s[4];
    #pragma unroll
    for (int j = 0; j < 4; ++j) {
        int e = blockIdx.x * 1024 + j * 256 + t;
        if (e < NE) {
            s[j] = ei[e];
            d[j] = ei[NE + e];
            atomicAdd(&hist[d[j] >> 8], 1);
        } else d[j] = -1;
    }
    __syncthreads();
    for (int i = t; i < NBIN; i += 256)
        base[i] = hist[i] ? atomicAdd(&bin_cursor[i], hist[i]) : 0;
    __syncthreads();
    #pragma unroll
    for (int j = 0; j < 4; ++j) {
        if (d[j] >= 0) {
            int b = d[j] >> 8;
            int o = atomicAdd(&lcur[b], 1);
            binbuf[base[b] + o] = (unsigned)s[j] | ((unsigned)(d[j] & 255) << 16);
        }
    }
}

// phase 3: one block per bin -> elist buckets (writes confined to 49KB window) + deg
__global__ __launch_bounds__(256) void k_bin3(const unsigned int* __restrict__ binbuf,
                                              const int* __restrict__ bin_start,
                                              unsigned short* __restrict__ elist,
                                              int* __restrict__ deg) {
    __shared__ int ldeg[256];
    int b = blockIdx.x, t = threadIdx.x;
    ldeg[t] = 0;
    __syncthreads();
    int lo = bin_start[b], hi = bin_start[b + 1];
    for (int i = lo + t; i < hi; i += 256) {
        unsigned v = binbuf[i];
        int src = v & 0xFFFF;
        int dl = v >> 16;
        int pos = atomicAdd(&ldeg[dl], 1);
        elist[(size_t)(b * 256 + dl) * CAP + pos] = (unsigned short)src;
    }
    __syncthreads();
    int node = b * 256 + t;
    if (node < NN) deg[node] = ldeg[t];
}

// ---------- aggregation (round-8 version: structural floor ~58 us) ----------
__global__ __launch_bounds__(256) void k_agg_bf(const unsigned short* __restrict__ h,
                                                const int* __restrict__ deg,
                                                const unsigned short* __restrict__ elist,
                                                unsigned short* __restrict__ z0) {
    int wave = threadIdx.x >> 6;
    int lane = threadIdx.x & 63;
    int node = blockIdx.x * 4 + wave;
    int chunk = lane & 31;
    int half = lane >> 5;
    const ushort8* h8 = (const ushort8*)h;

    float acc[8];
    if (half == 0) {
        ushort8 own = h8[(size_t)node * 32 + chunk];
        #pragma unroll
        for (int j = 0; j < 8; ++j) acc[j] = bf2f(own[j]);
    } else {
        #pragma unroll
        for (int j = 0; j < 8; ++j) acc[j] = 0.f;
    }

    int n = deg[node];
    const unsigned short* el = elist + (size_t)node * CAP;
    int i = 0;
    for (; i + 8 <= n; i += 8) {
        ushort8 sv = *(const ushort8*)(el + i);
        int i0 = half ? sv[1] : sv[0];
        int i1 = half ? sv[3] : sv[2];
        int i2 = half ? sv[5] : sv[4];
        int i3 = half ? sv[7] : sv[6];
        ushort8 r0 = h8[(size_t)i0 * 32 + chunk];
        ushort8 r1 = h8[(size_t)i1 * 32 + chunk];
        ushort8 r2 = h8[(size_t)i2 * 32 + chunk];
        ushort8 r3 = h8[(size_t)i3 * 32 + chunk];
        #pragma unroll
        for (int j = 0; j < 8; ++j) acc[j] += bf2f(r0[j]);
        #pragma unroll
        for (int j = 0; j < 8; ++j) acc[j] += bf2f(r1[j]);
        #pragma unroll
        for (int j = 0; j < 8; ++j) acc[j] += bf2f(r2[j]);
        #pragma unroll
        for (int j = 0; j < 8; ++j) acc[j] += bf2f(r3[j]);
    }
    for (; i < n; i += 2) {
        int s0 = el[i];
        int s1 = (i + 1 < n) ? (int)el[i + 1] : NN;
        int idx = half ? s1 : s0;
        ushort8 r = h8[(size_t)idx * 32 + chunk];
        #pragma unroll
        for (int j = 0; j < 8; ++j) acc[j] += bf2f(r[j]);
    }

    ushort8 o;
    #pragma unroll
    for (int j = 0; j < 8; ++j) {
        float other = __shfl_xor(acc[j], 32);
        o[j] = f2bf(acc[j] + other);
    }
    if (half == 0) ((ushort8*)z0)[(size_t)node * 32 + chunk] = o;
}

// ---------- fused MLP: relu(relu(z@W1+b1)@W2+b2) + BN partial stats ----------
__global__ __launch_bounds__(512, 2) void k_mlp(const unsigned short* __restrict__ A,
                                                const unsigned short* __restrict__ BT1,
                                                const unsigned short* __restrict__ BT2,
                                                const float* __restrict__ b1,
                                                const float* __restrict__ b2,
                                                float* __restrict__ Cout,
                                                float* __restrict__ pstat) {
    __shared__ short As[128 * 64];
    __shared__ short Bs[256 * 64];
    __shared__ short H1[128 * 256];
    __shared__ float spart[2][256][2];
    int tid = threadIdx.x;
    int lane = tid & 63;
    int wave = tid >> 6;
    int wr = wave >> 2, wc = wave & 3;
    long m0 = (long)blockIdx.x * 128;
    const int r = lane & 15, hi = lane >> 4;

    f32x4 acc[4][4];
    #pragma unroll
    for (int m = 0; m < 4; ++m)
        #pragma unroll
        for (int n = 0; n < 4; ++n)
            acc[m][n] = (f32x4){0.f, 0.f, 0.f, 0.f};

    for (int k0 = 0; k0 < DD; k0 += 64) {
        #pragma unroll
        for (int p = 0; p < 2; ++p) {
            int flat = p * 512 + tid;
            int row = flat >> 3, c8 = flat & 7;
            int slot = c8 ^ (row & 7);
            *(bf16x8*)(As + row * 64 + slot * 8) =
                *(const bf16x8*)(A + (m0 + row) * DD + k0 + c8 * 8);
        }
        #pragma unroll
        for (int p = 0; p < 4; ++p) {
            int flat = p * 512 + tid;
            int row = flat >> 3, c8 = flat & 7;
            int slot = c8 ^ (row & 7);
            *(bf16x8*)(Bs + row * 64 + slot * 8) =
                *(const bf16x8*)(BT1 + (long)row * DD + k0 + c8 * 8);
        }
        __syncthreads();
        bf16x8 af[4][2], bfr[4][2];
        #pragma unroll
        for (int m = 0; m < 4; ++m) {
            int row = wr * 64 + m * 16 + r;
            #pragma unroll
            for (int kk = 0; kk < 2; ++kk) {
                int slot = (kk * 4 + hi) ^ (row & 7);
                af[m][kk] = *(const bf16x8*)(As + row * 64 + slot * 8);
            }
        }
        #pragma unroll
        for (int n = 0; n < 4; ++n) {
            int col = wc * 64 + n * 16 + r;
            #pragma unroll
            for (int kk = 0; kk < 2; ++kk) {
                int slot = (kk * 4 + hi) ^ (col & 7);
                bfr[n][kk] = *(const bf16x8*)(Bs + col * 64 + slot * 8);
            }
        }
        #pragma unroll
        for (int kk = 0; kk < 2; ++kk)
            #pragma unroll
            for (int m = 0; m < 4; ++m)
                #pragma unroll
                for (int n = 0; n < 4; ++n)
                    acc[m][n] = __builtin_amdgcn_mfma_f32_16x16x32_bf16(af[m][kk], bfr[n][kk], acc[m][n], 0, 0, 0);
        __syncthreads();
    }

    #pragma unroll
    for (int n = 0; n < 4; ++n) {
        int col = wc * 64 + n * 16 + r;
        float bv = b1[col];
        int g = col >> 3, j8 = col & 7;
        #pragma unroll
        for (int m = 0; m < 4; ++m) {
            #pragma unroll
            for (int j = 0; j < 4; ++j) {
                int row = wr * 64 + m * 16 + hi * 4 + j;
                float v = acc[m][n][j] + bv;
                v = v > 0.f ? v : 0.f;
                H1[row * 256 + (g ^ (row & 7)) * 8 + j8] = (short)f2bf(v);
            }
        }
    }
    #pragma unroll
    for (int m = 0; m < 4; ++m)
        #pragma unroll
        for (int n = 0; n < 4; ++n)
            acc[m][n] = (f32x4){0.f, 0.f, 0.f, 0.f};
    __syncthreads();

    for (int k0 = 0; k0 < DD; k0 += 64) {
        #pragma unroll
        for (int p = 0; p < 4; ++p) {
            int flat = p * 512 + tid;
            int row = flat >> 3, c8 = flat & 7;
            int slot = c8 ^ (row & 7);
            *(bf16x8*)(Bs + row * 64 + slot * 8) =
                *(const bf16x8*)(BT2 + (long)row * DD + k0 + c8 * 8);
        }
        __syncthreads();
        bf16x8 af[4][2], bfr[4][2];
        #pragma unroll
        for (int m = 0; m < 4; ++m) {
            int row = wr * 64 + m * 16 + r;
            #pragma unroll
            for (int kk = 0; kk < 2; ++kk) {
                int g = (k0 >> 3) + kk * 4 + hi;
                af[m][kk] = *(const bf16x8*)(H1 + row * 256 + (g ^ (row & 7)) * 8);
            }
        }
        #pragma unroll
        for (int n = 0; n < 4; ++n) {
            int col = wc * 64 + n * 16 + r;
            #pragma unroll
            for (int kk = 0; kk < 2; ++kk) {
                int slot = (kk * 4 + hi) ^ (col & 7);
                bfr[n][kk] = *(const bf16x8*)(Bs + col * 64 + slot * 8);
            }
        }
        #pragma unroll
        for (int kk = 0; kk < 2; ++kk)
            #pragma unroll
            for (int m = 0; m < 4; ++m)
                #pragma unroll
                for (int n = 0; n < 4; ++n)
                    acc[m][n] = __builtin_amdgcn_mfma_f32_16x16x32_bf16(af[m][kk], bfr[n][kk], acc[m][n], 0, 0, 0);
        __syncthreads();
    }

    #pragma unroll
    for (int n = 0; n < 4; ++n) {
        int col = wc * 64 + n * 16 + r;
        float bv = b2[col];
        float cs = 0.f, cs2 = 0.f;
        #pragma unroll
        for (int m = 0; m < 4; ++m) {
            #pragma unroll
            for (int j = 0; j < 4; ++j) {
                long grow = m0 + wr * 64 + m * 16 + hi * 4 + j;
                float v = acc[m][n][j] + bv;
                v = v > 0.f ? v : 0.f;
                Cout[grow * DD + col] = v;
                float vm = (grow < NN) ? v : 0.f;
                cs += vm; cs2 += vm * vm;
            }
        }
        cs  += __shfl_xor(cs, 16);  cs  += __shfl_xor(cs, 32);
        cs2 += __shfl_xor(cs2, 16); cs2 += __shfl_xor(cs2, 32);
        if (hi == 0) {
            spart[wr][col][0] = cs;
            spart[wr][col][1] = cs2;
        }
    }
    __syncthreads();
    if (tid < 256) {
        float s  = spart[0][tid][0] + spart[1][tid][0];
        float s2 = spart[0][tid][1] + spart[1][tid][1];
        pstat[(size_t)blockIdx.x * 512 + tid] = s;
        pstat[(size_t)blockIdx.x * 512 + 256 + tid] = s2;
    }
}

// reduce per-block partials -> BN scale/shift (one block per column, fixed tree)
__global__ __launch_bounds__(256) void k_bnscale2(const float* __restrict__ pstat,
                                                  const float* __restrict__ gamma,
                                                  const float* __restrict__ beta,
                                                  float* __restrict__ ss) {
    int c = blockIdx.x;
    int t = threadIdx.x;
    float s = 0.f, s2 = 0.f;
    for (int mb = t; mb < NMB; mb += 256) {
        s  += pstat[(size_t)mb * 512 + c];
        s2 += pstat[(size_t)mb * 512 + 256 + c];
    }
    __shared__ float rs[256], rs2[256];
    rs[t] = s; rs2[t] = s2;
    __syncthreads();
    #pragma unroll
    for (int d = 128; d > 0; d >>= 1) {
        if (t < d) { rs[t] += rs[t + d]; rs2[t] += rs2[t + d]; }
        __syncthreads();
    }
    if (t == 0) {
        float mean = rs[0] * (1.0f / NN);
        float var = rs2[0] * (1.0f / NN) - mean * mean;
        float sc = gamma[c] * rsqrtf(var + BN_EPS);
        ss[c] = sc;
        ss[DD + c] = beta[c] - mean * sc;
    }
}

// fused BN-apply + bf16 emit + pool; grid (NG, 2): col-half per blockIdx.y.
template<int LAST>
__global__ __launch_bounds__(512) void k_bnpool(const float* __restrict__ z,
                                                const float* __restrict__ ss,
                                                const int* __restrict__ gstart,
                                                unsigned short* __restrict__ hbf,
                                                float* __restrict__ out, int layer) {
    __shared__ float4 red[16][32];
    int g = blockIdx.x;
    int ch = blockIdx.y;
    int t = threadIdx.x;
    int q = t & 31, rg = t >> 5;
    int cq = ch * 32 + q;
    float4 sc = ((const float4*)ss)[cq];
    float4 sh = ((const float4*)(ss + DD))[cq];
    int lo = gstart[g], hi = gstart[g + 1];
    float4 s = {0.f, 0.f, 0.f, 0.f};
    const float4* z4 = (const float4*)z;
    ushort4* h4 = (ushort4*)hbf;
    for (int r = lo + rg; r < hi; r += 16) {
        float4 v = z4[(size_t)r * 64 + cq];
        v.x = v.x * sc.x + sh.x;
        v.y = v.y * sc.y + sh.y;
        v.z = v.z * sc.z + sh.z;
        v.w = v.w * sc.w + sh.w;
        s.x += v.x; s.y += v.y; s.z += v.z; s.w += v.w;
        if (!LAST) {
            ushort4 o;
            o.x = f2bf(v.x); o.y = f2bf(v.y); o.z = f2bf(v.z); o.w = f2bf(v.w);
            h4[(size_t)r * 64 + cq] = o;
        }
    }
    red[rg][q] = s;
    __syncthreads();
    #pragma unroll
    for (int d = 8; d > 0; d >>= 1) {
        if (rg < d) {
            float4 a = red[rg][q], b = red[rg + d][q];
            a.x += b.x; a.y += b.y; a.z += b.z; a.w += b.w;
            red[rg][q] = a;
        }
        __syncthreads();
    }
    if (rg == 0) {
        ((float4*)(out + (size_t)g * (NL * DD) + layer * DD))[cq] = red[0][q];
    }
}

extern "C" void kernel_launch(void* const* d_in, const int* in_sizes, int n_in,
                              void* d_out, int out_size, void* d_ws, size_t ws_size,
                              hipStream_t stream) {
    const float* x     = (const float*)d_in[0];
    const int*   ei    = (const int*)d_in[1];
    const int*   batch = (const int*)d_in[2];
    const float* w1    = (const float*)d_in[3];
    const float* b1    = (const float*)d_in[4];
    const float* w2    = (const float*)d_in[5];
    const float* b2    = (const float*)d_in[6];
    const float* gamma = (const float*)d_in[7];
    const float* beta  = (const float*)d_in[8];
    float* out = (float*)d_out;

    char* ws = (char*)d_ws;
    size_t off = 0;
    auto alloc = [&](size_t bytes) -> void* {
        void* p = ws + off;
        off += (bytes + 255) & ~size_t(255);
        return p;
    };
    float*          buf0 = (float*)alloc((size_t)MPAD * DD * 4);                 // fp32 MLP out
    unsigned short* zbf  = (unsigned short*)alloc((size_t)MPAD * DD * 2);        // agg out (MLP A)
    unsigned short* hbf  = (unsigned short*)alloc((size_t)(NN + 64) * DD * 2);   // h bf16 + sentinel
    unsigned short* wt   = (unsigned short*)alloc((size_t)6 * DD * DD * 2);
    int* deg    = (int*)alloc((size_t)NN * 4);
    unsigned short* elist = (unsigned short*)alloc((size_t)NN * CAP * 2);
    unsigned int* binbuf = (unsigned int*)alloc((size_t)NE * 4);
    int* bin_cnt    = (int*)alloc(NBIN * 4);
    int* bin_start  = (int*)alloc((NBIN + 1) * 4);
    int* bin_cursor = (int*)alloc(NBIN * 4);
    int* gstart = (int*)alloc((size_t)(NG + 1) * 4);
    float* pstat = (float*)alloc((size_t)NMB * 512 * 4);
    float* ss   = (float*)alloc(2 * DD * 4);

    k_setup<<<(RTOT + 255) / 256, 256, 0, stream>>>(x, w1, w2, batch, hbf, wt, zbf, gstart, bin_cnt);
    const int EB = (NE + 1023) / 1024;   // 782
    k_bin1<<<EB, 256, 0, stream>>>(ei, bin_cnt);
    k_binscan<<<1, 256, 0, stream>>>(bin_cnt, bin_start, bin_cursor);
    k_bin2<<<EB, 256, 0, stream>>>(ei, bin_cursor, binbuf);
    k_bin3<<<NBIN, 256, 0, stream>>>(binbuf, bin_start, elist, deg);

    for (int l = 0; l < NL; ++l) {
        k_agg_bf<<<NN / 4, 256, 0, stream>>>(hbf, deg, elist, zbf);
        k_mlp<<<NMB, 512, 0, stream>>>(zbf, wt + (size_t)l * DD * DD,
                                       wt + (size_t)(3 + l) * DD * DD,
                                       b1 + l * DD, b2 + l * DD, buf0, pstat);
        k_bnscale2<<<DD, 256, 0, stream>>>(pstat, gamma + l * DD, beta + l * DD, ss);
        if (l < NL - 1)
            k_bnpool<0><<<dim3(NG, 2), 512, 0, stream>>>(buf0, ss, gstart, hbf, out, l);
        else
            k_bnpool<1><<<dim3(NG, 2), 512, 0, stream>>>(buf0, ss, gstart, hbf, out, l);
    }
}

// Round 12
// 393.340 us; speedup vs baseline: 1.1579x; 1.0051x over previous
//
#include <hip/hip_runtime.h>

#define NN 50000
#define NE 800000
#define NG 256
#define DD 256
#define NL 3
#define BN_EPS 1e-5f
#define MPAD 50048   // 782 * 64
#define CAP 96       // per-node edge bucket capacity
#define MB2 782      // MPAD / 64 (m-blocks for fused MLP)
#define NBIN 196     // ceil(NN/256) dst bins

typedef short bf16x8 __attribute__((ext_vector_type(8)));
typedef float f32x4 __attribute__((ext_vector_type(4)));
typedef unsigned short ushort8 __attribute__((ext_vector_type(8)));

__device__ __forceinline__ unsigned short f2bf(float f) {
    unsigned int u = __float_as_uint(f);
    u += 0x7FFFu + ((u >> 16) & 1u);
    return (unsigned short)(u >> 16);
}
__device__ __forceinline__ float bf2f(unsigned short s) {
    return __uint_as_float(((unsigned int)s) << 16);
}

// ---------- fused setup: f2bf(x), wconv, zpad, zrow, gbounds, bin_cnt=0 ----------
#define R0 3200000          // f2bf float4 groups (NN*DD/4)
#define R1 393216           // wconv elems (6*65536)
#define R2 12288            // zpad elems ((MPAD-NN)*DD)
#define R3 256              // zrow (sentinel row)
#define R4 256              // gbounds
#define R5 NBIN             // bin_cnt zero
#define RTOT (R0 + R1 + R2 + R3 + R4 + R5)

__global__ void k_setup(const float* __restrict__ x, const float* __restrict__ w1,
                        const float* __restrict__ w2, const int* __restrict__ batch,
                        unsigned short* __restrict__ hbf, unsigned short* __restrict__ wt,
                        unsigned short* __restrict__ zbf, int* __restrict__ gstart,
                        int* __restrict__ bin_cnt) {
    int i = blockIdx.x * blockDim.x + threadIdx.x;
    if (i < R0) {
        float4 v = ((const float4*)x)[i];
        ushort4 o;
        o.x = f2bf(v.x); o.y = f2bf(v.y); o.z = f2bf(v.z); o.w = f2bf(v.w);
        ((ushort4*)hbf)[i] = o;
        return;
    }
    i -= R0;
    if (i < R1) {
        int mat = i >> 16;
        int n = (i >> 8) & 255;
        int k = i & 255;
        const float* src = (mat < 3) ? (w1 + ((size_t)mat << 16)) : (w2 + ((size_t)(mat - 3) << 16));
        wt[i] = f2bf(src[k * 256 + n]);
        return;
    }
    i -= R1;
    if (i < R2) { zbf[NN * DD + i] = 0; return; }
    i -= R2;
    if (i < R3) { hbf[(size_t)NN * DD + i] = 0; return; }
    i -= R3;
    if (i < R4) {
        int g = i;
        int lo = 0, hi = NN;
        while (lo < hi) {
            int mid = (lo + hi) >> 1;
            if (batch[mid] < g) lo = mid + 1; else hi = mid;
        }
        gstart[g] = lo;
        if (g == 0) gstart[NG] = NN;
        return;
    }
    i -= R4;
    if (i < R5) bin_cnt[i] = 0;
}

// ---------- binned CSR build (kills dirty-line write amplification) ----------
__global__ __launch_bounds__(256) void k_bin1(const int* __restrict__ ei,
                                              int* __restrict__ bin_cnt) {
    __shared__ int hist[NBIN];
    int t = threadIdx.x;
    for (int i = t; i < NBIN; i += 256) hist[i] = 0;
    __syncthreads();
    #pragma unroll
    for (int j = 0; j < 4; ++j) {
        int e = blockIdx.x * 1024 + j * 256 + t;
        if (e < NE) atomicAdd(&hist[ei[NE + e] >> 8], 1);
    }
    __syncthreads();
    for (int i = t; i < NBIN; i += 256)
        if (hist[i]) atomicAdd(&bin_cnt[i], hist[i]);
}

__global__ void k_binscan(const int* __restrict__ bin_cnt, int* __restrict__ bin_start,
                          int* __restrict__ bin_cursor) {
    __shared__ int s[256];
    int t = threadIdx.x;
    int v = (t < NBIN) ? bin_cnt[t] : 0;
    s[t] = v;
    __syncthreads();
    #pragma unroll
    for (int d = 1; d < 256; d <<= 1) {
        int a = (t >= d) ? s[t - d] : 0;
        __syncthreads();
        s[t] += a;
        __syncthreads();
    }
    int excl = s[t] - v;
    if (t < NBIN) { bin_start[t] = excl; bin_cursor[t] = excl; }
    if (t == 0) bin_start[NBIN] = NE;
}

__global__ __launch_bounds__(256) void k_bin2(const int* __restrict__ ei,
                                              int* __restrict__ bin_cursor,
                                              unsigned int* __restrict__ binbuf) {
    __shared__ int hist[NBIN], base[NBIN], lcur[NBIN];
    int t = threadIdx.x;
    for (int i = t; i < NBIN; i += 256) { hist[i] = 0; lcur[i] = 0; }
    __syncthreads();
    int d[4], s[4];
    #pragma unroll
    for (int j = 0; j < 4; ++j) {
        int e = blockIdx.x * 1024 + j * 256 + t;
        if (e < NE) {
            s[j] = ei[e];
            d[j] = ei[NE + e];
            atomicAdd(&hist[d[j] >> 8], 1);
        } else d[j] = -1;
    }
    __syncthreads();
    for (int i = t; i < NBIN; i += 256)
        base[i] = hist[i] ? atomicAdd(&bin_cursor[i], hist[i]) : 0;
    __syncthreads();
    #pragma unroll
    for (int j = 0; j < 4; ++j) {
        if (d[j] >= 0) {
            int b = d[j] >> 8;
            int o = atomicAdd(&lcur[b], 1);
            binbuf[base[b] + o] = (unsigned)s[j] | ((unsigned)(d[j] & 255) << 16);
        }
    }
}

__global__ __launch_bounds__(256) void k_bin3(const unsigned int* __restrict__ binbuf,
                                              const int* __restrict__ bin_start,
                                              unsigned short* __restrict__ elist,
                                              int* __restrict__ deg) {
    __shared__ int ldeg[256];
    int b = blockIdx.x, t = threadIdx.x;
    ldeg[t] = 0;
    __syncthreads();
    int lo = bin_start[b], hi = bin_start[b + 1];
    for (int i = lo + t; i < hi; i += 256) {
        unsigned v = binbuf[i];
        int src = v & 0xFFFF;
        int dl = v >> 16;
        int pos = atomicAdd(&ldeg[dl], 1);
        elist[(size_t)(b * 256 + dl) * CAP + pos] = (unsigned short)src;
    }
    __syncthreads();
    int node = b * 256 + t;
    if (node < NN) deg[node] = ldeg[t];
}

// ---------- aggregation (structural floor ~58 us: compulsory per-XCD misses) ----------
__global__ __launch_bounds__(256) void k_agg_bf(const unsigned short* __restrict__ h,
                                                const int* __restrict__ deg,
                                                const unsigned short* __restrict__ elist,
                                                unsigned short* __restrict__ z0) {
    int wave = threadIdx.x >> 6;
    int lane = threadIdx.x & 63;
    int node = blockIdx.x * 4 + wave;
    int chunk = lane & 31;
    int half = lane >> 5;
    const ushort8* h8 = (const ushort8*)h;

    float acc[8];
    if (half == 0) {
        ushort8 own = h8[(size_t)node * 32 + chunk];
        #pragma unroll
        for (int j = 0; j < 8; ++j) acc[j] = bf2f(own[j]);
    } else {
        #pragma unroll
        for (int j = 0; j < 8; ++j) acc[j] = 0.f;
    }

    int n = deg[node];
    const unsigned short* el = elist + (size_t)node * CAP;
    int i = 0;
    for (; i + 8 <= n; i += 8) {
        ushort8 sv = *(const ushort8*)(el + i);
        int i0 = half ? sv[1] : sv[0];
        int i1 = half ? sv[3] : sv[2];
        int i2 = half ? sv[5] : sv[4];
        int i3 = half ? sv[7] : sv[6];
        ushort8 r0 = h8[(size_t)i0 * 32 + chunk];
        ushort8 r1 = h8[(size_t)i1 * 32 + chunk];
        ushort8 r2 = h8[(size_t)i2 * 32 + chunk];
        ushort8 r3 = h8[(size_t)i3 * 32 + chunk];
        #pragma unroll
        for (int j = 0; j < 8; ++j) acc[j] += bf2f(r0[j]);
        #pragma unroll
        for (int j = 0; j < 8; ++j) acc[j] += bf2f(r1[j]);
        #pragma unroll
        for (int j = 0; j < 8; ++j) acc[j] += bf2f(r2[j]);
        #pragma unroll
        for (int j = 0; j < 8; ++j) acc[j] += bf2f(r3[j]);
    }
    for (; i < n; i += 2) {
        int s0 = el[i];
        int s1 = (i + 1 < n) ? (int)el[i + 1] : NN;
        int idx = half ? s1 : s0;
        ushort8 r = h8[(size_t)idx * 32 + chunk];
        #pragma unroll
        for (int j = 0; j < 8; ++j) acc[j] += bf2f(r[j]);
    }

    ushort8 o;
    #pragma unroll
    for (int j = 0; j < 8; ++j) {
        float other = __shfl_xor(acc[j], 32);
        o[j] = f2bf(acc[j] + other);
    }
    if (half == 0) ((ushort8*)z0)[(size_t)node * 32 + chunk] = o;
}

// ---------- fused MLP: relu(relu(z@W1+b1)@W2+b2) + BN partial stats ----------
// BM=64, 256 threads (4 waves, each 64x64 via wc), LDS 74KB -> 2 blocks/CU.
__global__ __launch_bounds__(256, 2) void k_mlp(const unsigned short* __restrict__ A,
                                                const unsigned short* __restrict__ BT1,
                                                const unsigned short* __restrict__ BT2,
                                                const float* __restrict__ b1,
                                                const float* __restrict__ b2,
                                                float* __restrict__ Cout,
                                                float* __restrict__ pstat) {
    __shared__ short As[64 * 64];      // z tile k-chunk (8 KB)
    __shared__ short Bs[256 * 64];     // W1T / W2T k-chunk (32 KB, reused)
    __shared__ short H1[64 * 256];     // h1 tile, group-swizzled (32 KB)
    __shared__ float spart[256][2];    // per-col sum/sumsq (2 KB)
    int tid = threadIdx.x;
    int lane = tid & 63;
    int wc = tid >> 6;                 // wave = output col quadrant
    long m0 = (long)blockIdx.x * 64;
    const int r = lane & 15, hi = lane >> 4;

    f32x4 acc[4][4];
    #pragma unroll
    for (int m = 0; m < 4; ++m)
        #pragma unroll
        for (int n = 0; n < 4; ++n)
            acc[m][n] = (f32x4){0.f, 0.f, 0.f, 0.f};

    // ---- GEMM1: h1 = relu(z @ W1 + b1) ----
    for (int k0 = 0; k0 < DD; k0 += 64) {
        #pragma unroll
        for (int p = 0; p < 2; ++p) {           // As: 512 chunks
            int flat = p * 256 + tid;
            int row = flat >> 3, c8 = flat & 7;
            int slot = c8 ^ (row & 7);
            *(bf16x8*)(As + row * 64 + slot * 8) =
                *(const bf16x8*)(A + (m0 + row) * DD + k0 + c8 * 8);
        }
        #pragma unroll
        for (int p = 0; p < 8; ++p) {           // Bs: 2048 chunks
            int flat = p * 256 + tid;
            int row = flat >> 3, c8 = flat & 7;
            int slot = c8 ^ (row & 7);
            *(bf16x8*)(Bs + row * 64 + slot * 8) =
                *(const bf16x8*)(BT1 + (long)row * DD + k0 + c8 * 8);
        }
        __syncthreads();
        bf16x8 af[4][2], bfr[4][2];
        #pragma unroll
        for (int m = 0; m < 4; ++m) {
            int row = m * 16 + r;
            #pragma unroll
            for (int kk = 0; kk < 2; ++kk) {
                int slot = (kk * 4 + hi) ^ (row & 7);
                af[m][kk] = *(const bf16x8*)(As + row * 64 + slot * 8);
            }
        }
        #pragma unroll
        for (int n = 0; n < 4; ++n) {
            int col = wc * 64 + n * 16 + r;
            #pragma unroll
            for (int kk = 0; kk < 2; ++kk) {
                int slot = (kk * 4 + hi) ^ (col & 7);
                bfr[n][kk] = *(const bf16x8*)(Bs + col * 64 + slot * 8);
            }
        }
        #pragma unroll
        for (int kk = 0; kk < 2; ++kk)
            #pragma unroll
            for (int m = 0; m < 4; ++m)
                #pragma unroll
                for (int n = 0; n < 4; ++n)
                    acc[m][n] = __builtin_amdgcn_mfma_f32_16x16x32_bf16(af[m][kk], bfr[n][kk], acc[m][n], 0, 0, 0);
        __syncthreads();
    }

    // h1 epilogue -> LDS (group-swizzled: group g stored at g^(row&7))
    #pragma unroll
    for (int n = 0; n < 4; ++n) {
        int col = wc * 64 + n * 16 + r;
        float bv = b1[col];
        int g = col >> 3, j8 = col & 7;
        #pragma unroll
        for (int m = 0; m < 4; ++m) {
            #pragma unroll
            for (int j = 0; j < 4; ++j) {
                int row = m * 16 + hi * 4 + j;
                float v = acc[m][n][j] + bv;
                v = v > 0.f ? v : 0.f;
                H1[row * 256 + (g ^ (row & 7)) * 8 + j8] = (short)f2bf(v);
            }
        }
    }
    #pragma unroll
    for (int m = 0; m < 4; ++m)
        #pragma unroll
        for (int n = 0; n < 4; ++n)
            acc[m][n] = (f32x4){0.f, 0.f, 0.f, 0.f};
    __syncthreads();

    // ---- GEMM2: y = relu(h1 @ W2 + b2) ----
    for (int k0 = 0; k0 < DD; k0 += 64) {
        #pragma unroll
        for (int p = 0; p < 8; ++p) {
            int flat = p * 256 + tid;
            int row = flat >> 3, c8 = flat & 7;
            int slot = c8 ^ (row & 7);
            *(bf16x8*)(Bs + row * 64 + slot * 8) =
                *(const bf16x8*)(BT2 + (long)row * DD + k0 + c8 * 8);
        }
        __syncthreads();
        bf16x8 af[4][2], bfr[4][2];
        #pragma unroll
        for (int m = 0; m < 4; ++m) {
            int row = m * 16 + r;
            #pragma unroll
            for (int kk = 0; kk < 2; ++kk) {
                int g = (k0 >> 3) + kk * 4 + hi;
                af[m][kk] = *(const bf16x8*)(H1 + row * 256 + (g ^ (row & 7)) * 8);
            }
        }
        #pragma unroll
        for (int n = 0; n < 4; ++n) {
            int col = wc * 64 + n * 16 + r;
            #pragma unroll
            for (int kk = 0; kk < 2; ++kk) {
                int slot = (kk * 4 + hi) ^ (col & 7);
                bfr[n][kk] = *(const bf16x8*)(Bs + col * 64 + slot * 8);
            }
        }
        #pragma unroll
        for (int kk = 0; kk < 2; ++kk)
            #pragma unroll
            for (int m = 0; m < 4; ++m)
                #pragma unroll
                for (int n = 0; n < 4; ++n)
                    acc[m][n] = __builtin_amdgcn_mfma_f32_16x16x32_bf16(af[m][kk], bfr[n][kk], acc[m][n], 0, 0, 0);
        __syncthreads();
    }

    // epilogue: bias + relu -> fp32 out, fused BN column partials
    #pragma unroll
    for (int n = 0; n < 4; ++n) {
        int col = wc * 64 + n * 16 + r;
        float bv = b2[col];
        float cs = 0.f, cs2 = 0.f;
        #pragma unroll
        for (int m = 0; m < 4; ++m) {
            #pragma unroll
            for (int j = 0; j < 4; ++j) {
                long grow = m0 + m * 16 + hi * 4 + j;
                float v = acc[m][n][j] + bv;
                v = v > 0.f ? v : 0.f;
                Cout[grow * DD + col] = v;
                float vm = (grow < NN) ? v : 0.f;
                cs += vm; cs2 += vm * vm;
            }
        }
        cs  += __shfl_xor(cs, 16);  cs  += __shfl_xor(cs, 32);
        cs2 += __shfl_xor(cs2, 16); cs2 += __shfl_xor(cs2, 32);
        if (hi == 0) {
            spart[col][0] = cs;
            spart[col][1] = cs2;
        }
    }
    __syncthreads();
    pstat[(size_t)blockIdx.x * 512 + tid] = spart[tid][0];
    pstat[(size_t)blockIdx.x * 512 + 256 + tid] = spart[tid][1];
}

// reduce per-block partials -> BN scale/shift (one block per column, fixed tree)
__global__ __launch_bounds__(256) void k_bnscale2(const float* __restrict__ pstat,
                                                  const float* __restrict__ gamma,
                                                  const float* __restrict__ beta,
                                                  float* __restrict__ ss) {
    int c = blockIdx.x;
    int t = threadIdx.x;
    float s = 0.f, s2 = 0.f;
    for (int mb = t; mb < MB2; mb += 256) {
        s  += pstat[(size_t)mb * 512 + c];
        s2 += pstat[(size_t)mb * 512 + 256 + c];
    }
    __shared__ float rs[256], rs2[256];
    rs[t] = s; rs2[t] = s2;
    __syncthreads();
    #pragma unroll
    for (int d = 128; d > 0; d >>= 1) {
        if (t < d) { rs[t] += rs[t + d]; rs2[t] += rs2[t + d]; }
        __syncthreads();
    }
    if (t == 0) {
        float mean = rs[0] * (1.0f / NN);
        float var = rs2[0] * (1.0f / NN) - mean * mean;
        float sc = gamma[c] * rsqrtf(var + BN_EPS);
        ss[c] = sc;
        ss[DD + c] = beta[c] - mean * sc;
    }
}

// fused BN-apply + bf16 emit + pool; grid (NG, 2): col-half per blockIdx.y.
template<int LAST>
__global__ __launch_bounds__(512) void k_bnpool(const float* __restrict__ z,
                                                const float* __restrict__ ss,
                                                const int* __restrict__ gstart,
                                                unsigned short* __restrict__ hbf,
                                                float* __restrict__ out, int layer) {
    __shared__ float4 red[16][32];
    int g = blockIdx.x;
    int ch = blockIdx.y;
    int t = threadIdx.x;
    int q = t & 31, rg = t >> 5;
    int cq = ch * 32 + q;
    float4 sc = ((const float4*)ss)[cq];
    float4 sh = ((const float4*)(ss + DD))[cq];
    int lo = gstart[g], hi = gstart[g + 1];
    float4 s = {0.f, 0.f, 0.f, 0.f};
    const float4* z4 = (const float4*)z;
    ushort4* h4 = (ushort4*)hbf;
    for (int r = lo + rg; r < hi; r += 16) {
        float4 v = z4[(size_t)r * 64 + cq];
        v.x = v.x * sc.x + sh.x;
        v.y = v.y * sc.y + sh.y;
        v.z = v.z * sc.z + sh.z;
        v.w = v.w * sc.w + sh.w;
        s.x += v.x; s.y += v.y; s.z += v.z; s.w += v.w;
        if (!LAST) {
            ushort4 o;
            o.x = f2bf(v.x); o.y = f2bf(v.y); o.z = f2bf(v.z); o.w = f2bf(v.w);
            h4[(size_t)r * 64 + cq] = o;
        }
    }
    red[rg][q] = s;
    __syncthreads();
    #pragma unroll
    for (int d = 8; d > 0; d >>= 1) {
        if (rg < d) {
            float4 a = red[rg][q], b = red[rg + d][q];
            a.x += b.x; a.y += b.y; a.z += b.z; a.w += b.w;
            red[rg][q] = a;
        }
        __syncthreads();
    }
    if (rg == 0) {
        ((float4*)(out + (size_t)g * (NL * DD) + layer * DD))[cq] = red[0][q];
    }
}

extern "C" void kernel_launch(void* const* d_in, const int* in_sizes, int n_in,
                              void* d_out, int out_size, void* d_ws, size_t ws_size,
                              hipStream_t stream) {
    const float* x     = (const float*)d_in[0];
    const int*   ei    = (const int*)d_in[1];
    const int*   batch = (const int*)d_in[2];
    const float* w1    = (const float*)d_in[3];
    const float* b1    = (const float*)d_in[4];
    const float* w2    = (const float*)d_in[5];
    const float* b2    = (const float*)d_in[6];
    const float* gamma = (const float*)d_in[7];
    const float* beta  = (const float*)d_in[8];
    float* out = (float*)d_out;

    char* ws = (char*)d_ws;
    size_t off = 0;
    auto alloc = [&](size_t bytes) -> void* {
        void* p = ws + off;
        off += (bytes + 255) & ~size_t(255);
        return p;
    };
    float*          buf0 = (float*)alloc((size_t)MPAD * DD * 4);                 // fp32 MLP out
    unsigned short* zbf  = (unsigned short*)alloc((size_t)MPAD * DD * 2);        // agg out (MLP A)
    unsigned short* hbf  = (unsigned short*)alloc((size_t)(NN + 64) * DD * 2);   // h bf16 + sentinel
    unsigned short* wt   = (unsigned short*)alloc((size_t)6 * DD * DD * 2);
    int* deg    = (int*)alloc((size_t)NN * 4);
    unsigned short* elist = (unsigned short*)alloc((size_t)NN * CAP * 2);
    unsigned int* binbuf = (unsigned int*)alloc((size_t)NE * 4);
    int* bin_cnt    = (int*)alloc(NBIN * 4);
    int* bin_start  = (int*)alloc((NBIN + 1) * 4);
    int* bin_cursor = (int*)alloc(NBIN * 4);
    int* gstart = (int*)alloc((size_t)(NG + 1) * 4);
    float* pstat = (float*)alloc((size_t)MB2 * 512 * 4);
    float* ss   = (float*)alloc(2 * DD * 4);

    k_setup<<<(RTOT + 255) / 256, 256, 0, stream>>>(x, w1, w2, batch, hbf, wt, zbf, gstart, bin_cnt);
    const int EB = (NE + 1023) / 1024;   // 782
    k_bin1<<<EB, 256, 0, stream>>>(ei, bin_cnt);
    k_binscan<<<1, 256, 0, stream>>>(bin_cnt, bin_start, bin_cursor);
    k_bin2<<<EB, 256, 0, stream>>>(ei, bin_cursor, binbuf);
    k_bin3<<<NBIN, 256, 0, stream>>>(binbuf, bin_start, elist, deg);

    for (int l = 0; l < NL; ++l) {
        k_agg_bf<<<NN / 4, 256, 0, stream>>>(hbf, deg, elist, zbf);
        k_mlp<<<MB2, 256, 0, stream>>>(zbf, wt + (size_t)l * DD * DD,
                                       wt + (size_t)(3 + l) * DD * DD,
                                       b1 + l * DD, b2 + l * DD, buf0, pstat);
        k_bnscale2<<<DD, 256, 0, stream>>>(pstat, gamma + l * DD, beta + l * DD, ss);
        if (l < NL - 1)
            k_bnpool<0><<<dim3(NG, 2), 512, 0, stream>>>(buf0, ss, gstart, hbf, out, l);
        else
            k_bnpool<1><<<dim3(NG, 2), 512, 0, stream>>>(buf0, ss, gstart, hbf, out, l);
    }
}

// Round 13
// 361.116 us; speedup vs baseline: 1.2612x; 1.0892x over previous
//
#include <hip/hip_runtime.h>

#define NN 50000
#define NE 800000
#define NG 256
#define DD 256
#define NL 3
#define BN_EPS 1e-5f
#define MPAD 50048   // 782 * 64
#define CAP 96       // per-node edge bucket capacity
#define MB2 782      // MPAD / 64 (m-blocks for fused MLP)
#define NBIN 196     // ceil(NN/256) dst bins
#define BINCAP 4608  // fixed binbuf window per bin (mean 4082, +8 sigma)

typedef short bf16x8 __attribute__((ext_vector_type(8)));
typedef float f32x4 __attribute__((ext_vector_type(4)));
typedef unsigned short ushort8 __attribute__((ext_vector_type(8)));

__device__ __forceinline__ unsigned short f2bf(float f) {
    unsigned int u = __float_as_uint(f);
    u += 0x7FFFu + ((u >> 16) & 1u);
    return (unsigned short)(u >> 16);
}
__device__ __forceinline__ float bf2f(unsigned short s) {
    return __uint_as_float(((unsigned int)s) << 16);
}

// ---------- fused setup: f2bf(x), wconv, zpad, zrow, gbounds, bin_cnt=0 ----------
#define R0 3200000          // f2bf float4 groups (NN*DD/4)
#define R1 393216           // wconv elems (6*65536)
#define R2 12288            // zpad elems ((MPAD-NN)*DD)
#define R3 256              // zrow (sentinel row)
#define R4 256              // gbounds
#define R5 NBIN             // bin_cnt zero
#define RTOT (R0 + R1 + R2 + R3 + R4 + R5)

__global__ void k_setup(const float* __restrict__ x, const float* __restrict__ w1,
                        const float* __restrict__ w2, const int* __restrict__ batch,
                        unsigned short* __restrict__ hbf, unsigned short* __restrict__ wt,
                        unsigned short* __restrict__ zbf, int* __restrict__ gstart,
                        int* __restrict__ bin_cnt) {
    int i = blockIdx.x * blockDim.x + threadIdx.x;
    if (i < R0) {
        float4 v = ((const float4*)x)[i];
        ushort4 o;
        o.x = f2bf(v.x); o.y = f2bf(v.y); o.z = f2bf(v.z); o.w = f2bf(v.w);
        ((ushort4*)hbf)[i] = o;
        return;
    }
    i -= R0;
    if (i < R1) {
        int mat = i >> 16;
        int n = (i >> 8) & 255;
        int k = i & 255;
        const float* src = (mat < 3) ? (w1 + ((size_t)mat << 16)) : (w2 + ((size_t)(mat - 3) << 16));
        wt[i] = f2bf(src[k * 256 + n]);
        return;
    }
    i -= R1;
    if (i < R2) { zbf[NN * DD + i] = 0; return; }
    i -= R2;
    if (i < R3) { hbf[(size_t)NN * DD + i] = 0; return; }
    i -= R3;
    if (i < R4) {
        int g = i;
        int lo = 0, hi = NN;
        while (lo < hi) {
            int mid = (lo + hi) >> 1;
            if (batch[mid] < g) lo = mid + 1; else hi = mid;
        }
        gstart[g] = lo;
        if (g == 0) gstart[NG] = NN;
        return;
    }
    i -= R4;
    if (i < R5) bin_cnt[i] = 0;
}

// ---------- binned CSR build, 2 kernels (fixed per-bin windows) ----------
// phase A: LDS histogram -> global cursor reservation -> packed records into bin window
__global__ __launch_bounds__(256) void k_bin2(const int* __restrict__ ei,
                                              int* __restrict__ bin_cnt,
                                              unsigned int* __restrict__ binbuf) {
    __shared__ int hist[NBIN], base[NBIN], lcur[NBIN];
    int t = threadIdx.x;
    for (int i = t; i < NBIN; i += 256) { hist[i] = 0; lcur[i] = 0; }
    __syncthreads();
    int d[4], s[4];
    #pragma unroll
    for (int j = 0; j < 4; ++j) {
        int e = blockIdx.x * 1024 + j * 256 + t;
        if (e < NE) {
            s[j] = ei[e];
            d[j] = ei[NE + e];
            atomicAdd(&hist[d[j] >> 8], 1);
        } else d[j] = -1;
    }
    __syncthreads();
    for (int i = t; i < NBIN; i += 256)
        base[i] = hist[i] ? atomicAdd(&bin_cnt[i], hist[i]) : 0;
    __syncthreads();
    #pragma unroll
    for (int j = 0; j < 4; ++j) {
        if (d[j] >= 0) {
            int b = d[j] >> 8;
            int o = atomicAdd(&lcur[b], 1);
            binbuf[(size_t)b * BINCAP + base[b] + o] = (unsigned)s[j] | ((unsigned)(d[j] & 255) << 16);
        }
    }
}

// phase B: one block per bin -> elist buckets (writes confined to 49KB window) + deg
__global__ __launch_bounds__(256) void k_bin3(const unsigned int* __restrict__ binbuf,
                                              const int* __restrict__ bin_cnt,
                                              unsigned short* __restrict__ elist,
                                              int* __restrict__ deg) {
    __shared__ int ldeg[256];
    int b = blockIdx.x, t = threadIdx.x;
    ldeg[t] = 0;
    __syncthreads();
    int cnt = bin_cnt[b];
    const unsigned int* bb = binbuf + (size_t)b * BINCAP;
    for (int i = t; i < cnt; i += 256) {
        unsigned v = bb[i];
        int src = v & 0xFFFF;
        int dl = v >> 16;
        int pos = atomicAdd(&ldeg[dl], 1);
        elist[(size_t)(b * 256 + dl) * CAP + pos] = (unsigned short)src;
    }
    __syncthreads();
    int node = b * 256 + t;
    if (node < NN) deg[node] = ldeg[t];
}

// ---------- aggregation (structural floor ~58 us: compulsory per-XCD misses) ----------
__global__ __launch_bounds__(256) void k_agg_bf(const unsigned short* __restrict__ h,
                                                const int* __restrict__ deg,
                                                const unsigned short* __restrict__ elist,
                                                unsigned short* __restrict__ z0) {
    int wave = threadIdx.x >> 6;
    int lane = threadIdx.x & 63;
    int node = blockIdx.x * 4 + wave;
    int chunk = lane & 31;
    int half = lane >> 5;
    const ushort8* h8 = (const ushort8*)h;

    float acc[8];
    if (half == 0) {
        ushort8 own = h8[(size_t)node * 32 + chunk];
        #pragma unroll
        for (int j = 0; j < 8; ++j) acc[j] = bf2f(own[j]);
    } else {
        #pragma unroll
        for (int j = 0; j < 8; ++j) acc[j] = 0.f;
    }

    int n = deg[node];
    const unsigned short* el = elist + (size_t)node * CAP;
    int i = 0;
    for (; i + 8 <= n; i += 8) {
        ushort8 sv = *(const ushort8*)(el + i);
        int i0 = half ? sv[1] : sv[0];
        int i1 = half ? sv[3] : sv[2];
        int i2 = half ? sv[5] : sv[4];
        int i3 = half ? sv[7] : sv[6];
        ushort8 r0 = h8[(size_t)i0 * 32 + chunk];
        ushort8 r1 = h8[(size_t)i1 * 32 + chunk];
        ushort8 r2 = h8[(size_t)i2 * 32 + chunk];
        ushort8 r3 = h8[(size_t)i3 * 32 + chunk];
        #pragma unroll
        for (int j = 0; j < 8; ++j) acc[j] += bf2f(r0[j]);
        #pragma unroll
        for (int j = 0; j < 8; ++j) acc[j] += bf2f(r1[j]);
        #pragma unroll
        for (int j = 0; j < 8; ++j) acc[j] += bf2f(r2[j]);
        #pragma unroll
        for (int j = 0; j < 8; ++j) acc[j] += bf2f(r3[j]);
    }
    for (; i < n; i += 2) {
        int s0 = el[i];
        int s1 = (i + 1 < n) ? (int)el[i + 1] : NN;
        int idx = half ? s1 : s0;
        ushort8 r = h8[(size_t)idx * 32 + chunk];
        #pragma unroll
        for (int j = 0; j < 8; ++j) acc[j] += bf2f(r[j]);
    }

    ushort8 o;
    #pragma unroll
    for (int j = 0; j < 8; ++j) {
        float other = __shfl_xor(acc[j], 32);
        o[j] = f2bf(acc[j] + other);
    }
    if (half == 0) ((ushort8*)z0)[(size_t)node * 32 + chunk] = o;
}

// ---------- fused MLP: relu(relu(z@W1+b1)@W2+b2) -> bf16 z + exact fp32 BN partials ----------
// BM=64, 256 threads (4 waves), LDS 74KB -> 2 blocks/CU.
__global__ __launch_bounds__(256, 2) void k_mlp(const unsigned short* __restrict__ A,
                                                const unsigned short* __restrict__ BT1,
                                                const unsigned short* __restrict__ BT2,
                                                const float* __restrict__ b1,
                                                const float* __restrict__ b2,
                                                unsigned short* __restrict__ Cout,
                                                float* __restrict__ pstat) {
    __shared__ short As[64 * 64];      // z tile k-chunk (8 KB)
    __shared__ short Bs[256 * 64];     // W1T / W2T k-chunk (32 KB, reused)
    __shared__ short H1[64 * 256];     // h1 tile, group-swizzled (32 KB)
    __shared__ float spart[256][2];    // per-col sum/sumsq (2 KB)
    int tid = threadIdx.x;
    int lane = tid & 63;
    int wc = tid >> 6;                 // wave = output col quadrant
    long m0 = (long)blockIdx.x * 64;
    const int r = lane & 15, hi = lane >> 4;

    f32x4 acc[4][4];
    #pragma unroll
    for (int m = 0; m < 4; ++m)
        #pragma unroll
        for (int n = 0; n < 4; ++n)
            acc[m][n] = (f32x4){0.f, 0.f, 0.f, 0.f};

    // ---- GEMM1: h1 = relu(z @ W1 + b1) ----
    for (int k0 = 0; k0 < DD; k0 += 64) {
        #pragma unroll
        for (int p = 0; p < 2; ++p) {
            int flat = p * 256 + tid;
            int row = flat >> 3, c8 = flat & 7;
            int slot = c8 ^ (row & 7);
            *(bf16x8*)(As + row * 64 + slot * 8) =
                *(const bf16x8*)(A + (m0 + row) * DD + k0 + c8 * 8);
        }
        #pragma unroll
        for (int p = 0; p < 8; ++p) {
            int flat = p * 256 + tid;
            int row = flat >> 3, c8 = flat & 7;
            int slot = c8 ^ (row & 7);
            *(bf16x8*)(Bs + row * 64 + slot * 8) =
                *(const bf16x8*)(BT1 + (long)row * DD + k0 + c8 * 8);
        }
        __syncthreads();
        bf16x8 af[4][2], bfr[4][2];
        #pragma unroll
        for (int m = 0; m < 4; ++m) {
            int row = m * 16 + r;
            #pragma unroll
            for (int kk = 0; kk < 2; ++kk) {
                int slot = (kk * 4 + hi) ^ (row & 7);
                af[m][kk] = *(const bf16x8*)(As + row * 64 + slot * 8);
            }
        }
        #pragma unroll
        for (int n = 0; n < 4; ++n) {
            int col = wc * 64 + n * 16 + r;
            #pragma unroll
            for (int kk = 0; kk < 2; ++kk) {
                int slot = (kk * 4 + hi) ^ (col & 7);
                bfr[n][kk] = *(const bf16x8*)(Bs + col * 64 + slot * 8);
            }
        }
        #pragma unroll
        for (int kk = 0; kk < 2; ++kk)
            #pragma unroll
            for (int m = 0; m < 4; ++m)
                #pragma unroll
                for (int n = 0; n < 4; ++n)
                    acc[m][n] = __builtin_amdgcn_mfma_f32_16x16x32_bf16(af[m][kk], bfr[n][kk], acc[m][n], 0, 0, 0);
        __syncthreads();
    }

    // h1 epilogue -> LDS (group-swizzled: group g stored at g^(row&7))
    #pragma unroll
    for (int n = 0; n < 4; ++n) {
        int col = wc * 64 + n * 16 + r;
        float bv = b1[col];
        int g = col >> 3, j8 = col & 7;
        #pragma unroll
        for (int m = 0; m < 4; ++m) {
            #pragma unroll
            for (int j = 0; j < 4; ++j) {
                int row = m * 16 + hi * 4 + j;
                float v = acc[m][n][j] + bv;
                v = v > 0.f ? v : 0.f;
                H1[row * 256 + (g ^ (row & 7)) * 8 + j8] = (short)f2bf(v);
            }
        }
    }
    #pragma unroll
    for (int m = 0; m < 4; ++m)
        #pragma unroll
        for (int n = 0; n < 4; ++n)
            acc[m][n] = (f32x4){0.f, 0.f, 0.f, 0.f};
    __syncthreads();

    // ---- GEMM2: y = relu(h1 @ W2 + b2) ----
    for (int k0 = 0; k0 < DD; k0 += 64) {
        #pragma unroll
        for (int p = 0; p < 8; ++p) {
            int flat = p * 256 + tid;
            int row = flat >> 3, c8 = flat & 7;
            int slot = c8 ^ (row & 7);
            *(bf16x8*)(Bs + row * 64 + slot * 8) =
                *(const bf16x8*)(BT2 + (long)row * DD + k0 + c8 * 8);
        }
        __syncthreads();
        bf16x8 af[4][2], bfr[4][2];
        #pragma unroll
        for (int m = 0; m < 4; ++m) {
            int row = m * 16 + r;
            #pragma unroll
            for (int kk = 0; kk < 2; ++kk) {
                int g = (k0 >> 3) + kk * 4 + hi;
                af[m][kk] = *(const bf16x8*)(H1 + row * 256 + (g ^ (row & 7)) * 8);
            }
        }
        #pragma unroll
        for (int n = 0; n < 4; ++n) {
            int col = wc * 64 + n * 16 + r;
            #pragma unroll
            for (int kk = 0; kk < 2; ++kk) {
                int slot = (kk * 4 + hi) ^ (col & 7);
                bfr[n][kk] = *(const bf16x8*)(Bs + col * 64 + slot * 8);
            }
        }
        #pragma unroll
        for (int kk = 0; kk < 2; ++kk)
            #pragma unroll
            for (int m = 0; m < 4; ++m)
                #pragma unroll
                for (int n = 0; n < 4; ++n)
                    acc[m][n] = __builtin_amdgcn_mfma_f32_16x16x32_bf16(af[m][kk], bfr[n][kk], acc[m][n], 0, 0, 0);
        __syncthreads();
    }

    // epilogue: bias + relu -> bf16 z out; BN partials from EXACT fp32 values
    #pragma unroll
    for (int n = 0; n < 4; ++n) {
        int col = wc * 64 + n * 16 + r;
        float bv = b2[col];
        float cs = 0.f, cs2 = 0.f;
        #pragma unroll
        for (int m = 0; m < 4; ++m) {
            #pragma unroll
            for (int j = 0; j < 4; ++j) {
                long grow = m0 + m * 16 + hi * 4 + j;
                float v = acc[m][n][j] + bv;
                v = v > 0.f ? v : 0.f;
                Cout[grow * DD + col] = f2bf(v);
                float vm = (grow < NN) ? v : 0.f;
                cs += vm; cs2 += vm * vm;
            }
        }
        cs  += __shfl_xor(cs, 16);  cs  += __shfl_xor(cs, 32);
        cs2 += __shfl_xor(cs2, 16); cs2 += __shfl_xor(cs2, 32);
        if (hi == 0) {
            spart[col][0] = cs;
            spart[col][1] = cs2;
        }
    }
    __syncthreads();
    pstat[(size_t)blockIdx.x * 512 + tid] = spart[tid][0];
    pstat[(size_t)blockIdx.x * 512 + 256 + tid] = spart[tid][1];
}

// reduce per-block partials -> BN scale/shift (one block per column, fixed tree)
__global__ __launch_bounds__(256) void k_bnscale2(const float* __restrict__ pstat,
                                                  const float* __restrict__ gamma,
                                                  const float* __restrict__ beta,
                                                  float* __restrict__ ss) {
    int c = blockIdx.x;
    int t = threadIdx.x;
    float s = 0.f, s2 = 0.f;
    for (int mb = t; mb < MB2; mb += 256) {
        s  += pstat[(size_t)mb * 512 + c];
        s2 += pstat[(size_t)mb * 512 + 256 + c];
    }
    __shared__ float rs[256], rs2[256];
    rs[t] = s; rs2[t] = s2;
    __syncthreads();
    #pragma unroll
    for (int d = 128; d > 0; d >>= 1) {
        if (t < d) { rs[t] += rs[t + d]; rs2[t] += rs2[t + d]; }
        __syncthreads();
    }
    if (t == 0) {
        float mean = rs[0] * (1.0f / NN);
        float var = rs2[0] * (1.0f / NN) - mean * mean;
        float sc = gamma[c] * rsqrtf(var + BN_EPS);
        ss[c] = sc;
        ss[DD + c] = beta[c] - mean * sc;
    }
}

// fused BN-apply + bf16 emit + pool over bf16 z; grid (NG, 2): col-half per blockIdx.y.
template<int LAST>
__global__ __launch_bounds__(512) void k_bnpool(const unsigned short* __restrict__ z,
                                                const float* __restrict__ ss,
                                                const int* __restrict__ gstart,
                                                unsigned short* __restrict__ hbf,
                                                float* __restrict__ out, int layer) {
    __shared__ float4 red[16][32];
    int g = blockIdx.x;
    int ch = blockIdx.y;
    int t = threadIdx.x;
    int q = t & 31, rg = t >> 5;
    int cq = ch * 32 + q;
    float4 sc = ((const float4*)ss)[cq];
    float4 sh = ((const float4*)(ss + DD))[cq];
    int lo = gstart[g], hi = gstart[g + 1];
    float4 s = {0.f, 0.f, 0.f, 0.f};
    const ushort4* z4 = (const ushort4*)z;
    ushort4* h4 = (ushort4*)hbf;
    for (int r = lo + rg; r < hi; r += 16) {
        ushort4 zv = z4[(size_t)r * 64 + cq];
        float4 v;
        v.x = bf2f(zv.x) * sc.x + sh.x;
        v.y = bf2f(zv.y) * sc.y + sh.y;
        v.z = bf2f(zv.z) * sc.z + sh.z;
        v.w = bf2f(zv.w) * sc.w + sh.w;
        s.x += v.x; s.y += v.y; s.z += v.z; s.w += v.w;
        if (!LAST) {
            ushort4 o;
            o.x = f2bf(v.x); o.y = f2bf(v.y); o.z = f2bf(v.z); o.w = f2bf(v.w);
            h4[(size_t)r * 64 + cq] = o;
        }
    }
    red[rg][q] = s;
    __syncthreads();
    #pragma unroll
    for (int d = 8; d > 0; d >>= 1) {
        if (rg < d) {
            float4 a = red[rg][q], b = red[rg + d][q];
            a.x += b.x; a.y += b.y; a.z += b.z; a.w += b.w;
            red[rg][q] = a;
        }
        __syncthreads();
    }
    if (rg == 0) {
        ((float4*)(out + (size_t)g * (NL * DD) + layer * DD))[cq] = red[0][q];
    }
}

extern "C" void kernel_launch(void* const* d_in, const int* in_sizes, int n_in,
                              void* d_out, int out_size, void* d_ws, size_t ws_size,
                              hipStream_t stream) {
    const float* x     = (const float*)d_in[0];
    const int*   ei    = (const int*)d_in[1];
    const int*   batch = (const int*)d_in[2];
    const float* w1    = (const float*)d_in[3];
    const float* b1    = (const float*)d_in[4];
    const float* w2    = (const float*)d_in[5];
    const float* b2    = (const float*)d_in[6];
    const float* gamma = (const float*)d_in[7];
    const float* beta  = (const float*)d_in[8];
    float* out = (float*)d_out;

    char* ws = (char*)d_ws;
    size_t off = 0;
    auto alloc = [&](size_t bytes) -> void* {
        void* p = ws + off;
        off += (bytes + 255) & ~size_t(255);
        return p;
    };
    unsigned short* zB   = (unsigned short*)alloc((size_t)MPAD * DD * 2);        // bf16 MLP out
    unsigned short* zbf  = (unsigned short*)alloc((size_t)MPAD * DD * 2);        // agg out (MLP A)
    unsigned short* hbf  = (unsigned short*)alloc((size_t)(NN + 64) * DD * 2);   // h bf16 + sentinel
    unsigned short* wt   = (unsigned short*)alloc((size_t)6 * DD * DD * 2);
    int* deg    = (int*)alloc((size_t)NN * 4);
    unsigned short* elist = (unsigned short*)alloc((size_t)NN * CAP * 2);
    unsigned int* binbuf = (unsigned int*)alloc((size_t)NBIN * BINCAP * 4);
    int* bin_cnt    = (int*)alloc(NBIN * 4);
    int* gstart = (int*)alloc((size_t)(NG + 1) * 4);
    float* pstat = (float*)alloc((size_t)MB2 * 512 * 4);
    float* ss   = (float*)alloc(2 * DD * 4);

    k_setup<<<(RTOT + 255) / 256, 256, 0, stream>>>(x, w1, w2, batch, hbf, wt, zbf, gstart, bin_cnt);
    const int EB = (NE + 1023) / 1024;   // 782
    k_bin2<<<EB, 256, 0, stream>>>(ei, bin_cnt, binbuf);
    k_bin3<<<NBIN, 256, 0, stream>>>(binbuf, bin_cnt, elist, deg);

    for (int l = 0; l < NL; ++l) {
        k_agg_bf<<<NN / 4, 256, 0, stream>>>(hbf, deg, elist, zbf);
        k_mlp<<<MB2, 256, 0, stream>>>(zbf, wt + (size_t)l * DD * DD,
                                       wt + (size_t)(3 + l) * DD * DD,
                                       b1 + l * DD, b2 + l * DD, zB, pstat);
        k_bnscale2<<<DD, 256, 0, stream>>>(pstat, gamma + l * DD, beta + l * DD, ss);
        if (l < NL - 1)
            k_bnpool<0><<<dim3(NG, 2), 512, 0, stream>>>(zB, ss, gstart, hbf, out, l);
        else
            k_bnpool<1><<<dim3(NG, 2), 512, 0, stream>>>(zB, ss, gstart, hbf, out, l);
    }
}